// Round 5
// baseline (721.570 us; speedup 1.0000x reference)
//
#include <hip/hip_runtime.h>
#include <hip/hip_bf16.h>
#include <math.h>

// RWKV-7 Tmix forward, B=4 T=1024 C=1024 H=16 N=64.
// R5: recurrence at 4 waves/SIMD (4096 waves, 1 row/wave, lane=j; DPP +
// swizzle + bpermute 64-lane reductions; 8-deep prefetch ring).
// stage1+bigrkv merged. Input dtype (f32 vs bf16) runtime-detected.

using bf16 = __hip_bfloat16;
typedef __attribute__((ext_vector_type(8))) short bf16x8;
typedef __attribute__((ext_vector_type(4))) float f32x4;

#define DEVINL __device__ __forceinline__

DEVINL float b2f(bf16 v) { return __bfloat162float(v); }
DEVINL bf16 f2b(float f) { return __float2bfloat16(f); }
DEVINL float sigm(float x) { return 1.f / (1.f + __expf(-x)); }
DEVINL float bfbits2f(unsigned short s) { return __uint_as_float(((unsigned)s) << 16); }
DEVINL float ldin(const void* p, size_t i, int fl) {
  return fl ? ((const float*)p)[i] : b2f(((const bf16*)p)[i]);
}

DEVINL void g2lds16(const void* g, void* l) {
  __builtin_amdgcn_global_load_lds(
      (__attribute__((address_space(1))) void*)(g),
      (__attribute__((address_space(3))) void*)(l), 16, 0, 0);
}

template<int CTRL>
DEVINL float dpp_add(float x) {
  int t = __builtin_amdgcn_update_dpp(0, __float_as_int(x), CTRL, 0xf, 0xf, true);
  return x + __int_as_float(t);
}
// full 64-lane sum, result in all lanes: 4x DPP row_ror + swizzle xor16 + bpermute xor32
DEVINL float rowsum64(float x, int bpx) {
  x = dpp_add<0x121>(x);
  x = dpp_add<0x122>(x);
  x = dpp_add<0x124>(x);
  x = dpp_add<0x128>(x);
  int t = __builtin_amdgcn_ds_swizzle(__float_as_int(x), 0x401F);  // xor 16
  x += __int_as_float(t);
  int u = __builtin_amdgcn_ds_bpermute(bpx, __float_as_int(x));    // xor 32
  return x + __int_as_float(u);
}

// ---------------- dtype probe: flag=1 -> inputs are f32 ----------------
__global__ void detect_kernel(const unsigned* __restrict__ x, int* __restrict__ flag) {
  __shared__ int cnt[4];
  int tid = threadIdx.x;
  unsigned w = x[tid];
  float v = fabsf(bfbits2f((unsigned short)(w & 0xffffu)));
  bool plaus = (v >= 1e-4f && v <= 16.f);
  unsigned long long m = __ballot(plaus);
  if ((tid & 63) == 0) cnt[tid >> 6] = __popcll(m);
  __syncthreads();
  if (tid == 0) *flag = (cnt[0] + cnt[1] + cnt[2] + cnt[3] < 128) ? 1 : 0;
}

// ---------------- prep: mix + big-weight cvt + 8 small transposes ----------------
__global__ __launch_bounds__(256)
void prep_kernel(const void* __restrict__ x,
    const void* mr, const void* mw, const void* mk,
    const void* mv, const void* ma, const void* mg,
    const void* W_r, const void* W_k, const void* W_v, const void* W_o,
    bf16* cWr, bf16* cWk, bf16* cWv, bf16* cWo,
    const void* w1, const void* w2, const void* a1, const void* a2,
    const void* v1, const void* v2, const void* g1, const void* g2,
    bf16* w1t, bf16* w2t, bf16* a1t, bf16* a2t,
    bf16* v1t, bf16* v2t, bf16* g1t, bf16* g2t,
    const int* __restrict__ flag,
    bf16* oxr, bf16* oxw, bf16* oxk, bf16* oxv, bf16* oxa, bf16* oxg)
{
  int fl = *flag;
  int bx = blockIdx.x;
  if (bx < 16384) {                       // token-shift mix over 4M
    size_t idx = (size_t)bx * 256 + threadIdx.x;
    int c = (int)(idx & 1023);
    int t = (int)((idx >> 10) & 1023);
    float xc = ldin(x, idx, fl);
    float px = (t == 0) ? 0.f : ldin(x, idx - 1024, fl);
    float dx = px - xc;
    oxr[idx] = f2b(xc + ldin(mr, c, fl) * dx);
    oxw[idx] = f2b(xc + ldin(mw, c, fl) * dx);
    oxk[idx] = f2b(xc + ldin(mk, c, fl) * dx);
    oxv[idx] = f2b(xc + ldin(mv, c, fl) * dx);
    oxa[idx] = f2b(xc + ldin(ma, c, fl) * dx);
    oxg[idx] = f2b(xc + ldin(mg, c, fl) * dx);
  } else if (bx < 32768) {                // big-weight convert, 4 x 1M
    int g = (bx - 16384) * 256 + threadIdx.x;
    int seg = g >> 20, i = g & 1048575;
    const void* s = seg == 0 ? W_r : seg == 1 ? W_k : seg == 2 ? W_v : W_o;
    bf16* d = seg == 0 ? cWr : seg == 1 ? cWk : seg == 2 ? cWv : cWo;
    d[i] = fl ? f2b(((const float*)s)[i]) : ((const bf16*)s)[i];
  } else {                                // 8 small transposes [K,N]->[N,K]
    int idx = (bx - 32768) * 256 + threadIdx.x;
    if (idx >= 655360) return;
    const int ends[8] = {65536, 131072, 196608, 262144, 294912, 327680, 491520, 655360};
    const int Ks[8] = {1024, 64, 1024, 64, 1024, 32, 1024, 160};
    const int Nd[8] = {64, 1024, 64, 1024, 32, 1024, 160, 1024};
    const void* srcs[8] = {w1, w2, a1, a2, v1, v2, g1, g2};
    bf16* dsts[8] = {w1t, w2t, a1t, a2t, v1t, v2t, g1t, g2t};
    int seg = 0, start = 0;
#pragma unroll
    for (int s2 = 0; s2 < 7; s2++)
      if (idx >= ends[s2]) { seg = s2 + 1; start = ends[s2]; }
    int local = idx - start;
    int K = Ks[seg], N = Nd[seg];
    int k = local / N, n = local - k * N;
    dsts[seg][(size_t)n * K + k] = f2b(ldin(srcs[seg], local, fl));
  }
}

// ---------------- shared MFMA GEMM core: C[M,N] = A[M,K] * B[N,K]^T ----------------
template<typename Epi>
DEVINL void gemm_core(const bf16* __restrict__ A, const bf16* __restrict__ Bt,
                      int K, int Brows, int m0, int n0, Epi&& epi)
{
  __shared__ short As[128 * 32];
  __shared__ short Bs[128 * 32];
  const int tid = threadIdx.x;
  const int wid = tid >> 6, lane = tid & 63;
  const int wr = (wid >> 1) * 64, wc = (wid & 1) * 64;

  f32x4 acc[4][4] = {};

  const int lrow = lane >> 2;
  const int lcol = (lane & 3) * 8;
  int arow0 = m0 + (wid * 2 + 0) * 16 + lrow;
  int arow1 = m0 + (wid * 2 + 1) * 16 + lrow;
  int brow0 = n0 + (wid * 2 + 0) * 16 + lrow; if (brow0 >= Brows) brow0 = Brows - 1;
  int brow1 = n0 + (wid * 2 + 1) * 16 + lrow; if (brow1 >= Brows) brow1 = Brows - 1;

  const short* Ag = (const short*)A;
  const short* Bg = (const short*)Bt;

  for (int kk = 0; kk < K; kk += 32) {
    __syncthreads();
    g2lds16(Ag + (size_t)arow0 * K + kk + lcol, As + (wid * 2 + 0) * 512);
    g2lds16(Ag + (size_t)arow1 * K + kk + lcol, As + (wid * 2 + 1) * 512);
    g2lds16(Bg + (size_t)brow0 * K + kk + lcol, Bs + (wid * 2 + 0) * 512);
    g2lds16(Bg + (size_t)brow1 * K + kk + lcol, Bs + (wid * 2 + 1) * 512);
    __syncthreads();
    bf16x8 af[4], bfr[4];
#pragma unroll
    for (int mi = 0; mi < 4; mi++)
      af[mi] = *(const bf16x8*)(As + (wr + mi * 16 + (lane & 15)) * 32 + (lane >> 4) * 8);
#pragma unroll
    for (int ni = 0; ni < 4; ni++)
      bfr[ni] = *(const bf16x8*)(Bs + (wc + ni * 16 + (lane & 15)) * 32 + (lane >> 4) * 8);
#pragma unroll
    for (int mi = 0; mi < 4; mi++)
#pragma unroll
      for (int ni = 0; ni < 4; ni++)
        acc[mi][ni] = __builtin_amdgcn_mfma_f32_16x16x32_bf16(af[mi], bfr[ni], acc[mi][ni], 0, 0, 0);
  }

  const int cl0 = lane & 15, r0 = (lane >> 4) * 4;
#pragma unroll
  for (int mi = 0; mi < 4; mi++)
#pragma unroll
    for (int ni = 0; ni < 4; ni++) {
      int col = n0 + wc + ni * 16 + cl0;
#pragma unroll
      for (int rr = 0; rr < 4; rr++)
        epi(m0 + wr + mi * 16 + r0 + rr, col, acc[mi][ni][rr]);
    }
}

// ---------------- mid: big r/k/v projections + low-rank stage1 ----------------
// z in 0..2: big GEMM -> PKb slots (0=r 1=kraw 2=v); z==3: stage1 via y-seg
__global__ __launch_bounds__(256)
void mid_kernel(const bf16* xr, const bf16* xk, const bf16* xv,
                const bf16* cWr, const bf16* cWk, const bf16* cWv,
                bf16* __restrict__ PKb,
                const bf16* xw, const bf16* xa, const bf16* xg,
                const bf16* w1t, const bf16* a1t, const bf16* v1t, const bf16* g1t,
                bf16* hw, bf16* ha, bf16* hv, bf16* hg)
{
  int z = blockIdx.z;
  if (z < 3) {
    const bf16* A  = z == 0 ? xr  : z == 1 ? xk  : xv;
    const bf16* Bt = z == 0 ? cWr : z == 1 ? cWk : cWv;
    gemm_core(A, Bt, 1024, 1024, blockIdx.x * 128, blockIdx.y * 128,
              [&](int row, int col, float f) {
      PKb[(size_t)row * 5120 + (col >> 6) * 320 + z * 64 + (col & 63)] = f2b(f);
    });
  } else {
    int y = blockIdx.y;
    if (y >= 5) return;
    int seg = (y <= 2) ? y : 3;
    int n0 = (y == 4) ? 128 : 0;
    const bf16* A  = seg == 0 ? xw  : seg == 1 ? xa  : seg == 2 ? xv  : xg;
    const bf16* Bt = seg == 0 ? w1t : seg == 1 ? a1t : seg == 2 ? v1t : g1t;
    int NS         = seg == 0 ? 64  : seg == 1 ? 64  : seg == 2 ? 32  : 160;
    bf16* out      = seg == 0 ? hw  : seg == 1 ? ha  : seg == 2 ? hv  : hg;
    gemm_core(A, Bt, 1024, NS, blockIdx.x * 128, n0, [&](int row, int col, float f) {
      if (col >= NS) return;
      if (seg == 0) f = tanhf(f);
      else if (seg == 3) f = sigm(f);
      out[(size_t)row * NS + col] = f2b(f);
    });
  }
}

// ---------------- stage2: wdec->PKw | asig->slot3 | vblend->slot2 | G ----------------
__global__ __launch_bounds__(256)
void stage2_kernel(const bf16* hw, const bf16* ha, const bf16* hv, const bf16* hg,
                   const bf16* w2t, const bf16* a2t, const bf16* v2t, const bf16* g2t,
                   bf16* __restrict__ PKb, float* __restrict__ PKw, float* __restrict__ G,
                   const void* w0, const void* a0, const void* v0p, const void* vfirst,
                   const int* __restrict__ flag)
{
  int fl = *flag;
  int z = blockIdx.z;
  const bf16* A  = z == 0 ? hw  : z == 1 ? ha  : z == 2 ? hv  : hg;
  const bf16* Bt = z == 0 ? w2t : z == 1 ? a2t : z == 2 ? v2t : g2t;
  int K          = z == 0 ? 64  : z == 1 ? 64  : z == 2 ? 32  : 160;
  gemm_core(A, Bt, K, 1024, blockIdx.x * 128, blockIdx.y * 128,
            [&](int row, int col, float f) {
    if (z == 0) {
      float zz = -(ldin(w0, col, fl) + f);
      float sp = fmaxf(zz, 0.f) + __logf(1.f + __expf(-fabsf(zz)));
      PKw[(size_t)row * 1024 + col] = __expf(-__expf(-sp - 0.5f));
    } else if (z == 1) {
      PKb[(size_t)row * 5120 + (col >> 6) * 320 + 192 + (col & 63)] =
          f2b(sigm(ldin(a0, col, fl) + f));
    } else if (z == 2) {
      float sg = sigm(ldin(v0p, col, fl) + f);
      size_t pa = (size_t)row * 5120 + (col >> 6) * 320 + 128 + (col & 63);
      float vr = b2f(PKb[pa]);
      float vf = ldin(vfirst, (size_t)row * 1024 + col, fl);
      PKb[pa] = f2b(vr + (vf - vr) * sg);
    } else {
      G[(size_t)row * 1024 + col] = f;
    }
  });
}

// ---------------- per-(t,h) finalize: kkn, b, k_final ----------------
// PKb slots: 0=r 1=kraw->kfinal 2=v 3=asig->kkn 4=b
__global__ __launch_bounds__(256)
void post_kernel(bf16* __restrict__ PKb, const void* __restrict__ kkw,
                 const void* __restrict__ kaw, const int* __restrict__ flag) {
  int fl = *flag;
  int slot = blockIdx.x * 4 + (threadIdx.x >> 6);
  int tg = slot >> 4, h = slot & 15;
  int n = threadIdx.x & 63, c = h * 64 + n;
  size_t pb = (size_t)tg * 5120 + (size_t)h * 320;
  float kraw = b2f(PKb[pb + 64 + n]);
  float asig = b2f(PKb[pb + 192 + n]);
  float kk = kraw * ldin(kkw, c, fl);
  float ss = kk * kk;
  ss += __shfl_xor(ss, 1);  ss += __shfl_xor(ss, 2);  ss += __shfl_xor(ss, 4);
  ss += __shfl_xor(ss, 8);  ss += __shfl_xor(ss, 16); ss += __shfl_xor(ss, 32);
  float kkn = kk / fmaxf(sqrtf(ss), 1e-12f);
  PKb[pb + 192 + n] = f2b(kkn);
  PKb[pb + 256 + n] = f2b(-kkn * asig);
  PKb[pb + 64 + n]  = f2b(kraw * (1.f + (asig - 1.f) * ldin(kaw, c, fl)));
}

// ---------------- sequential recurrence: 1 row/wave, 4 waves/SIMD ----------------
// 4096 blocks x 64 thr. blk: bh = blk&63 (64 sibs per bh, same XCD), i = blk>>6.
// lane = j in [0,64). S[i][j] in 1 VGPR. No LDS/barriers; RD-deep ring.
// Overreads <=8 steps past PKb (80KB, lands in PKw) and PKw (32KB, lands in hw).
#define RD 8
__global__ __launch_bounds__(64, 4)
void recur_kernel(const bf16* __restrict__ PKb, const float* __restrict__ PKw,
                  float* __restrict__ Y) {
  int blk = blockIdx.x;
  int bh = blk & 63, i = blk >> 6;
  int b = bh >> 4, h = bh & 15;
  int lane = threadIdx.x;                       // j

  const char* baseB = (const char*)PKb + (size_t)b * 1024 * 10240 + h * 640 + lane * 2;
  const char* baseV = (const char*)PKb + (size_t)b * 1024 * 10240 + h * 640 + 256 + i * 2;
  const char* baseW = (const char*)PKw + (size_t)b * 1024 * 4096 + h * 256 + (size_t)lane * 4;
  float* yout = Y + (size_t)b * 1024 * 1024 + h * 64 + i;
  const int bpx = (lane ^ 32) << 2;             // bpermute addr for xor-32

  unsigned short Rr[RD], Rk[RD], Ra[RD], Rb[RD], Rv[RD];
  float Rw[RD];
#pragma unroll
  for (int d = 0; d < RD; ++d) {
    const char* pB = baseB + (size_t)d * 10240;
    Rr[d] = *(const unsigned short*)(pB);            // slot0 r
    Rk[d] = *(const unsigned short*)(pB + 128);      // slot1 kfinal
    Ra[d] = *(const unsigned short*)(pB + 384);      // slot3 kkn
    Rb[d] = *(const unsigned short*)(pB + 512);      // slot4 b
    Rv[d] = *(const unsigned short*)(baseV + (size_t)d * 10240);
    Rw[d] = *(const float*)(baseW + (size_t)d * 4096);
  }

  float S = 0.f;
  for (int t0 = 0; t0 < 1024; t0 += RD) {
#pragma unroll
    for (int d = 0; d < RD; ++d) {
      float r = bfbits2f(Rr[d]), k = bfbits2f(Rk[d]);
      float a = bfbits2f(Ra[d]), bb = bfbits2f(Rb[d]);
      float vi = bfbits2f(Rv[d]), w = Rw[d];
      {  // prefetch step t0+d+RD into slot d
        size_t tn = (size_t)(t0 + d + RD);
        const char* pB = baseB + tn * 10240;
        Rr[d] = *(const unsigned short*)(pB);
        Rk[d] = *(const unsigned short*)(pB + 128);
        Ra[d] = *(const unsigned short*)(pB + 384);
        Rb[d] = *(const unsigned short*)(pB + 512);
        Rv[d] = *(const unsigned short*)(baseV + tn * 10240);
        Rw[d] = *(const float*)(baseW + tn * 4096);
      }
      float sa = rowsum64(S * a, bpx);
      S = S * w + sa * bb + vi * k;
      float y = rowsum64(S * r, bpx);
      if (lane == 0) yout[(size_t)(t0 + d) * 1024] = y;
    }
  }
}

// ---------------- GroupNorm + residual + g gate ----------------
__global__ __launch_bounds__(256)
void gn_kernel(const float* __restrict__ Y, const bf16* __restrict__ PKb,
               const float* __restrict__ G,
               const void* __restrict__ gw, const void* __restrict__ gb,
               const void* __restrict__ rk, const int* __restrict__ flag,
               bf16* __restrict__ Z)
{
  int fl = *flag;
  int slot = blockIdx.x * 4 + (threadIdx.x >> 6);
  int tg = slot >> 4, h = slot & 15;
  int n = threadIdx.x & 63, c = h * 64 + n;
  size_t pb = (size_t)tg * 5120 + (size_t)h * 320;
  float y = Y[(size_t)tg * 1024 + c];
  float rr = b2f(PKb[pb + n]), kf = b2f(PKb[pb + 64 + n]), vv = b2f(PKb[pb + 128 + n]);
  float s1 = y, s2 = y * y, s3 = rr * kf * ldin(rk, c, fl);
#pragma unroll
  for (int m = 1; m < 64; m <<= 1) {
    s1 += __shfl_xor(s1, m);
    s2 += __shfl_xor(s2, m);
    s3 += __shfl_xor(s3, m);
  }
  float mu = s1 * 0.015625f;
  float var = s2 * 0.015625f - mu * mu;
  float xn = (y - mu) * rsqrtf(var + 0.00064f);
  float yn = xn * ldin(gw, c, fl) + ldin(gb, c, fl);
  yn += s3 * vv;
  Z[(size_t)tg * 1024 + c] = f2b(yn * G[(size_t)tg * 1024 + c]);
}

// ---------------- final output GEMM ----------------
__global__ __launch_bounds__(256)
void outgemm_kernel(const bf16* Z, const bf16* cWo,
                    float* oF, bf16* oB, const int* __restrict__ flag)
{
  int fl = *flag;
  gemm_core(Z, cWo, 1024, 1024, blockIdx.x * 128, blockIdx.y * 128,
            [&](int row, int col, float f) {
    if (fl) oF[(size_t)row * 1024 + col] = f;
    else    oB[(size_t)row * 1024 + col] = f2b(f);
  });
}

extern "C" void kernel_launch(void* const* d_in, const int* in_sizes, int n_in,
                              void* d_out, int out_size, void* d_ws, size_t ws_size,
                              hipStream_t stream)
{
  const void* x      = d_in[0];
  const void* vfirst = d_in[1];
  const void* m_r = d_in[2];  const void* m_w = d_in[3];
  const void* m_k = d_in[4];  const void* m_v = d_in[5];
  const void* m_a = d_in[6];  const void* m_g = d_in[7];
  const void* w0  = d_in[8];  const void* w1  = d_in[9];  const void* w2  = d_in[10];
  const void* a0  = d_in[11]; const void* a1  = d_in[12]; const void* a2  = d_in[13];
  const void* v0p = d_in[14]; const void* v1  = d_in[15]; const void* v2  = d_in[16];
  const void* g1  = d_in[17]; const void* g2  = d_in[18];
  const void* k_k = d_in[19]; const void* k_a = d_in[20]; const void* r_k = d_in[21];
  const void* W_r = d_in[22]; const void* W_k = d_in[23];
  const void* W_v = d_in[24]; const void* W_o = d_in[25];
  const void* gnw = d_in[26]; const void* gnb = d_in[27];
  (void)in_sizes; (void)n_in; (void)out_size; (void)ws_size;

  char* ws = (char*)d_ws;
  size_t off = 0;
  auto alloc = [&](size_t bytes) -> void* {
    void* p = ws + off; off += (bytes + 255) & ~(size_t)255; return p;
  };
  const size_t BTC2 = (size_t)4096 * 1024 * 2;
  int*  flag = (int*)alloc(256);
  bf16* cWr = (bf16*)alloc((size_t)1048576 * 2);
  bf16* cWk = (bf16*)alloc((size_t)1048576 * 2);
  bf16* cWv = (bf16*)alloc((size_t)1048576 * 2);
  bf16* cWo = (bf16*)alloc((size_t)1048576 * 2);
  bf16* w1t = (bf16*)alloc((size_t)65536 * 2);
  bf16* w2t = (bf16*)alloc((size_t)65536 * 2);
  bf16* a1t = (bf16*)alloc((size_t)65536 * 2);
  bf16* a2t = (bf16*)alloc((size_t)65536 * 2);
  bf16* v1t = (bf16*)alloc((size_t)32768 * 2);
  bf16* v2t = (bf16*)alloc((size_t)32768 * 2);
  bf16* g1t = (bf16*)alloc((size_t)163840 * 2);
  bf16* g2t = (bf16*)alloc((size_t)163840 * 2);
  bf16* xr = (bf16*)alloc(BTC2);
  bf16* xw = (bf16*)alloc(BTC2);
  bf16* xk = (bf16*)alloc(BTC2);
  bf16* xv = (bf16*)alloc(BTC2);
  bf16* xa = (bf16*)alloc(BTC2);
  bf16* xg = (bf16*)alloc(BTC2);
  bf16* PKb = (bf16*)alloc((size_t)4096 * 5120 * 2);   // [BT][H][5][64]
  float* PKw = (float*)alloc((size_t)4096 * 1024 * 4); // [BT][C] wdec
  bf16* hw  = (bf16*)alloc((size_t)4096 * 64 * 2);
  bf16* ha  = (bf16*)alloc((size_t)4096 * 64 * 2);
  bf16* hv  = (bf16*)alloc((size_t)4096 * 32 * 2);
  bf16* hg  = (bf16*)alloc((size_t)4096 * 160 * 2);
  // dead-buffer reuse (lifetimes verified by launch order):
  float* G = (float*)xr;   // over xr+xw; written by stage2 (after mid consumes)
  float* Y = (float*)xk;   // over xk+xv; written by recur
  bf16*  Z = xa;           // written by gn (after mid consumes xa)

  detect_kernel<<<1, 256, 0, stream>>>((const unsigned*)x, flag);
  prep_kernel<<<35328, 256, 0, stream>>>(
      x, m_r, m_w, m_k, m_v, m_a, m_g,
      W_r, W_k, W_v, W_o, cWr, cWk, cWv, cWo,
      w1, w2, a1, a2, v1, v2, g1, g2,
      w1t, w2t, a1t, a2t, v1t, v2t, g1t, g2t,
      flag, xr, xw, xk, xv, xa, xg);

  mid_kernel<<<dim3(32, 8, 4), 256, 0, stream>>>(xr, xk, xv, cWr, cWk, cWv, PKb,
                                                 xw, xa, xg, w1t, a1t, v1t, g1t,
                                                 hw, ha, hv, hg);
  stage2_kernel<<<dim3(32, 8, 4), 256, 0, stream>>>(hw, ha, hv, hg,
                                                    w2t, a2t, v2t, g2t,
                                                    PKb, PKw, G, w0, a0, v0p, vfirst, flag);
  post_kernel<<<16384, 256, 0, stream>>>(PKb, k_k, k_a, flag);
  recur_kernel<<<4096, 64, 0, stream>>>(PKb, PKw, Y);
  gn_kernel<<<16384, 256, 0, stream>>>(Y, PKb, G, gnw, gnb, r_k, flag, Z);
  outgemm_kernel<<<dim3(32, 8), 256, 0, stream>>>(Z, cWo, (float*)d_out, (bf16*)d_out, flag);
}

// Round 7
// 672.684 us; speedup vs baseline: 1.0727x; 1.0727x over previous
//
#include <hip/hip_runtime.h>
#include <hip/hip_bf16.h>
#include <math.h>

// RWKV-7 Tmix forward, B=4 T=1024 C=1024 H=16 N=64.
// R6b: recurrence back to 4 rows/wave (R3 decomposition, 264us baseline) with
// the y-off-critical-path identity: y_i = S_old.(w*r) + sa_i*(b.r) + v_i*(k.r);
// dual interleaved DPP reductions; (k.r),(b.r) precomputed in post_kernel.
// Input dtype (f32 vs bf16) runtime-detected.

using bf16 = __hip_bfloat16;
typedef __attribute__((ext_vector_type(8))) short bf16x8;
typedef __attribute__((ext_vector_type(4))) float f32x4;

#define DEVINL __device__ __forceinline__

DEVINL float b2f(bf16 v) { return __bfloat162float(v); }
DEVINL bf16 f2b(float f) { return __float2bfloat16(f); }
DEVINL float sigm(float x) { return 1.f / (1.f + __expf(-x)); }
DEVINL float bfbits2f(unsigned short s) { return __uint_as_float(((unsigned)s) << 16); }
DEVINL float ldin(const void* p, size_t i, int fl) {
  return fl ? ((const float*)p)[i] : b2f(((const bf16*)p)[i]);
}

DEVINL void g2lds16(const void* g, void* l) {
  __builtin_amdgcn_global_load_lds(
      (__attribute__((address_space(1))) void*)(g),
      (__attribute__((address_space(3))) void*)(l), 16, 0, 0);
}

template<int CTRL>
DEVINL float dpp_add(float x) {
  int t = __builtin_amdgcn_update_dpp(0, __float_as_int(x), CTRL, 0xf, 0xf, true);
  return x + __int_as_float(t);
}
// two independent 16-lane-row sums, DPP stages interleaved to overlap latency
DEVINL void rowsum16x2(float& p, float& q) {
  p = dpp_add<0x121>(p); q = dpp_add<0x121>(q);   // row_ror:1
  p = dpp_add<0x122>(p); q = dpp_add<0x122>(q);   // row_ror:2
  p = dpp_add<0x124>(p); q = dpp_add<0x124>(q);   // row_ror:4
  p = dpp_add<0x128>(p); q = dpp_add<0x128>(q);   // row_ror:8
}

// ---------------- dtype probe: flag=1 -> inputs are f32 ----------------
__global__ void detect_kernel(const unsigned* __restrict__ x, int* __restrict__ flag) {
  __shared__ int cnt[4];
  int tid = threadIdx.x;
  unsigned w = x[tid];
  float v = fabsf(bfbits2f((unsigned short)(w & 0xffffu)));
  bool plaus = (v >= 1e-4f && v <= 16.f);
  unsigned long long m = __ballot(plaus);
  if ((tid & 63) == 0) cnt[tid >> 6] = __popcll(m);
  __syncthreads();
  if (tid == 0) *flag = (cnt[0] + cnt[1] + cnt[2] + cnt[3] < 128) ? 1 : 0;
}

// ---------------- prep: mix + big-weight cvt + 8 small transposes ----------------
__global__ __launch_bounds__(256)
void prep_kernel(const void* __restrict__ x,
    const void* mr, const void* mw, const void* mk,
    const void* mv, const void* ma, const void* mg,
    const void* W_r, const void* W_k, const void* W_v, const void* W_o,
    bf16* cWr, bf16* cWk, bf16* cWv, bf16* cWo,
    const void* w1, const void* w2, const void* a1, const void* a2,
    const void* v1, const void* v2, const void* g1, const void* g2,
    bf16* w1t, bf16* w2t, bf16* a1t, bf16* a2t,
    bf16* v1t, bf16* v2t, bf16* g1t, bf16* g2t,
    const int* __restrict__ flag,
    bf16* oxr, bf16* oxw, bf16* oxk, bf16* oxv, bf16* oxa, bf16* oxg)
{
  int fl = *flag;
  int bx = blockIdx.x;
  if (bx < 16384) {                       // token-shift mix over 4M
    size_t idx = (size_t)bx * 256 + threadIdx.x;
    int c = (int)(idx & 1023);
    int t = (int)((idx >> 10) & 1023);
    float xc = ldin(x, idx, fl);
    float px = (t == 0) ? 0.f : ldin(x, idx - 1024, fl);
    float dx = px - xc;
    oxr[idx] = f2b(xc + ldin(mr, c, fl) * dx);
    oxw[idx] = f2b(xc + ldin(mw, c, fl) * dx);
    oxk[idx] = f2b(xc + ldin(mk, c, fl) * dx);
    oxv[idx] = f2b(xc + ldin(mv, c, fl) * dx);
    oxa[idx] = f2b(xc + ldin(ma, c, fl) * dx);
    oxg[idx] = f2b(xc + ldin(mg, c, fl) * dx);
  } else if (bx < 32768) {                // big-weight convert, 4 x 1M
    int g = (bx - 16384) * 256 + threadIdx.x;
    int seg = g >> 20, i = g & 1048575;
    const void* s = seg == 0 ? W_r : seg == 1 ? W_k : seg == 2 ? W_v : W_o;
    bf16* d = seg == 0 ? cWr : seg == 1 ? cWk : seg == 2 ? cWv : cWo;
    d[i] = fl ? f2b(((const float*)s)[i]) : ((const bf16*)s)[i];
  } else {                                // 8 small transposes [K,N]->[N,K]
    int idx = (bx - 32768) * 256 + threadIdx.x;
    if (idx >= 655360) return;
    const int ends[8] = {65536, 131072, 196608, 262144, 294912, 327680, 491520, 655360};
    const int Ks[8] = {1024, 64, 1024, 64, 1024, 32, 1024, 160};
    const int Nd[8] = {64, 1024, 64, 1024, 32, 1024, 160, 1024};
    const void* srcs[8] = {w1, w2, a1, a2, v1, v2, g1, g2};
    bf16* dsts[8] = {w1t, w2t, a1t, a2t, v1t, v2t, g1t, g2t};
    int seg = 0, start = 0;
#pragma unroll
    for (int s2 = 0; s2 < 7; s2++)
      if (idx >= ends[s2]) { seg = s2 + 1; start = ends[s2]; }
    int local = idx - start;
    int K = Ks[seg], N = Nd[seg];
    int k = local / N, n = local - k * N;
    dsts[seg][(size_t)n * K + k] = f2b(ldin(srcs[seg], local, fl));
  }
}

// ---------------- shared MFMA GEMM core: C[M,N] = A[M,K] * B[N,K]^T ----------------
template<typename Epi>
DEVINL void gemm_core(const bf16* __restrict__ A, const bf16* __restrict__ Bt,
                      int K, int Brows, int m0, int n0, Epi&& epi)
{
  __shared__ short As[128 * 32];
  __shared__ short Bs[128 * 32];
  const int tid = threadIdx.x;
  const int wid = tid >> 6, lane = tid & 63;
  const int wr = (wid >> 1) * 64, wc = (wid & 1) * 64;

  f32x4 acc[4][4] = {};

  const int lrow = lane >> 2;
  const int lcol = (lane & 3) * 8;
  int arow0 = m0 + (wid * 2 + 0) * 16 + lrow;
  int arow1 = m0 + (wid * 2 + 1) * 16 + lrow;
  int brow0 = n0 + (wid * 2 + 0) * 16 + lrow; if (brow0 >= Brows) brow0 = Brows - 1;
  int brow1 = n0 + (wid * 2 + 1) * 16 + lrow; if (brow1 >= Brows) brow1 = Brows - 1;

  const short* Ag = (const short*)A;
  const short* Bg = (const short*)Bt;

  for (int kk = 0; kk < K; kk += 32) {
    __syncthreads();
    g2lds16(Ag + (size_t)arow0 * K + kk + lcol, As + (wid * 2 + 0) * 512);
    g2lds16(Ag + (size_t)arow1 * K + kk + lcol, As + (wid * 2 + 1) * 512);
    g2lds16(Bg + (size_t)brow0 * K + kk + lcol, Bs + (wid * 2 + 0) * 512);
    g2lds16(Bg + (size_t)brow1 * K + kk + lcol, Bs + (wid * 2 + 1) * 512);
    __syncthreads();
    bf16x8 af[4], bfr[4];
#pragma unroll
    for (int mi = 0; mi < 4; mi++)
      af[mi] = *(const bf16x8*)(As + (wr + mi * 16 + (lane & 15)) * 32 + (lane >> 4) * 8);
#pragma unroll
    for (int ni = 0; ni < 4; ni++)
      bfr[ni] = *(const bf16x8*)(Bs + (wc + ni * 16 + (lane & 15)) * 32 + (lane >> 4) * 8);
#pragma unroll
    for (int mi = 0; mi < 4; mi++)
#pragma unroll
      for (int ni = 0; ni < 4; ni++)
        acc[mi][ni] = __builtin_amdgcn_mfma_f32_16x16x32_bf16(af[mi], bfr[ni], acc[mi][ni], 0, 0, 0);
  }

  const int cl0 = lane & 15, r0 = (lane >> 4) * 4;
#pragma unroll
  for (int mi = 0; mi < 4; mi++)
#pragma unroll
    for (int ni = 0; ni < 4; ni++) {
      int col = n0 + wc + ni * 16 + cl0;
#pragma unroll
      for (int rr = 0; rr < 4; rr++)
        epi(m0 + wr + mi * 16 + r0 + rr, col, acc[mi][ni][rr]);
    }
}

// ---------------- stage1: xw@w1 tanh | xa@a1 | xv@v1 | xg@g1 sigm ----------------
__global__ __launch_bounds__(256)
void stage1_kernel(const bf16* xw, const bf16* xa, const bf16* xv, const bf16* xg,
                   const bf16* w1t, const bf16* a1t, const bf16* v1t, const bf16* g1t,
                   bf16* hw, bf16* ha, bf16* hv, bf16* hg)
{
  int y = blockIdx.y;
  int seg = (y <= 2) ? y : 3;
  int n0 = (y == 4) ? 128 : 0;
  const bf16* A  = seg == 0 ? xw  : seg == 1 ? xa  : seg == 2 ? xv  : xg;
  const bf16* Bt = seg == 0 ? w1t : seg == 1 ? a1t : seg == 2 ? v1t : g1t;
  int NS         = seg == 0 ? 64  : seg == 1 ? 64  : seg == 2 ? 32  : 160;
  bf16* out      = seg == 0 ? hw  : seg == 1 ? ha  : seg == 2 ? hv  : hg;
  gemm_core(A, Bt, 1024, NS, blockIdx.x * 128, n0, [&](int row, int col, float f) {
    if (col >= NS) return;
    if (seg == 0) f = tanhf(f);
    else if (seg == 3) f = sigm(f);
    out[(size_t)row * NS + col] = f2b(f);
  });
}

// ---------------- big r/k/v projections -> PKb slots 0/1/2 ----------------
// PKb slots: 0=r 1=kraw->kfinal 2=v 3=asig->kkn 4=b
__global__ __launch_bounds__(256)
void bigrkv_kernel(const bf16* xr, const bf16* xk, const bf16* xv,
                   const bf16* cWr, const bf16* cWk, const bf16* cWv,
                   bf16* __restrict__ PKb)
{
  int z = blockIdx.z;
  const bf16* A  = z == 0 ? xr  : z == 1 ? xk  : xv;
  const bf16* Bt = z == 0 ? cWr : z == 1 ? cWk : cWv;
  gemm_core(A, Bt, 1024, 1024, blockIdx.x * 128, blockIdx.y * 128,
            [&](int row, int col, float f) {
    PKb[(size_t)row * 5120 + (col >> 6) * 320 + z * 64 + (col & 63)] = f2b(f);
  });
}

// ---------------- stage2: wdec->PKw | asig->slot3 | vblend->slot2 | G ----------------
__global__ __launch_bounds__(256)
void stage2_kernel(const bf16* hw, const bf16* ha, const bf16* hv, const bf16* hg,
                   const bf16* w2t, const bf16* a2t, const bf16* v2t, const bf16* g2t,
                   bf16* __restrict__ PKb, float* __restrict__ PKw, float* __restrict__ G,
                   const void* w0, const void* a0, const void* v0p, const void* vfirst,
                   const int* __restrict__ flag)
{
  int fl = *flag;
  int z = blockIdx.z;
  const bf16* A  = z == 0 ? hw  : z == 1 ? ha  : z == 2 ? hv  : hg;
  const bf16* Bt = z == 0 ? w2t : z == 1 ? a2t : z == 2 ? v2t : g2t;
  int K          = z == 0 ? 64  : z == 1 ? 64  : z == 2 ? 32  : 160;
  gemm_core(A, Bt, K, 1024, blockIdx.x * 128, blockIdx.y * 128,
            [&](int row, int col, float f) {
    if (z == 0) {
      float zz = -(ldin(w0, col, fl) + f);
      float sp = fmaxf(zz, 0.f) + __logf(1.f + __expf(-fabsf(zz)));
      PKw[(size_t)row * 1024 + col] = __expf(-__expf(-sp - 0.5f));
    } else if (z == 1) {
      PKb[(size_t)row * 5120 + (col >> 6) * 320 + 192 + (col & 63)] =
          f2b(sigm(ldin(a0, col, fl) + f));
    } else if (z == 2) {
      float sg = sigm(ldin(v0p, col, fl) + f);
      size_t pa = (size_t)row * 5120 + (col >> 6) * 320 + 128 + (col & 63);
      float vr = b2f(PKb[pa]);
      float vf = ldin(vfirst, (size_t)row * 1024 + col, fl);
      PKb[pa] = f2b(vr + (vf - vr) * sg);
    } else {
      G[(size_t)row * 1024 + col] = f;
    }
  });
}

// ---------------- per-(t,h) finalize: kkn, b, k_final + (k.r),(b.r) scalars ----------------
// PKb slots: 0=r 1=kraw->kfinal 2=v 3=asig->kkn 4=b ; PKs[tg*32+h*2] = {k.r, b.r}
__global__ __launch_bounds__(256)
void post_kernel(bf16* __restrict__ PKb, float* __restrict__ PKs,
                 const void* __restrict__ kkw, const void* __restrict__ kaw,
                 const int* __restrict__ flag) {
  int fl = *flag;
  int slot = blockIdx.x * 4 + (threadIdx.x >> 6);
  int tg = slot >> 4, h = slot & 15;
  int n = threadIdx.x & 63, c = h * 64 + n;
  size_t pb = (size_t)tg * 5120 + (size_t)h * 320;
  float rr   = b2f(PKb[pb + n]);
  float kraw = b2f(PKb[pb + 64 + n]);
  float asig = b2f(PKb[pb + 192 + n]);
  float kk = kraw * ldin(kkw, c, fl);
  float ss = kk * kk;
  ss += __shfl_xor(ss, 1);  ss += __shfl_xor(ss, 2);  ss += __shfl_xor(ss, 4);
  ss += __shfl_xor(ss, 8);  ss += __shfl_xor(ss, 16); ss += __shfl_xor(ss, 32);
  float kkn = kk / fmaxf(sqrtf(ss), 1e-12f);
  float bv = -kkn * asig;
  float kf = kraw * (1.f + (asig - 1.f) * ldin(kaw, c, fl));
  PKb[pb + 192 + n] = f2b(kkn);
  PKb[pb + 256 + n] = f2b(bv);
  PKb[pb + 64 + n]  = f2b(kf);
  // dot(k_final, r) and dot(b, r) over the 64-lane head
  float kr = kf * rr, br = bv * rr;
#pragma unroll
  for (int m = 1; m < 64; m <<= 1) {
    kr += __shfl_xor(kr, m);
    br += __shfl_xor(br, m);
  }
  if (n == 0) {
    PKs[(size_t)tg * 32 + h * 2]     = kr;
    PKs[(size_t)tg * 32 + h * 2 + 1] = br;
  }
}

// ---------------- sequential recurrence: 4 rows/wave + y off critical path ----------------
// 1024 blocks x 64 thr. blk = sib*64 + bh (16 sibs per bh, same XCD).
// lane: rl=lane>>4 (row in [sib*4..+4)), jq=lane&15 (4 j's). Pure-DPP reductions.
// Per step: p = S.a ; q = S.(w*r) (independent, dual-interleaved reduction);
//           y_i = q + p*(b.r) + v_i*(k.r) ; S = S*w + p*b + v_i*k.
// Overreads <=8 steps past PKb (lands in PKw), PKw (lands in PKs), PKs (lands in hw).
#define RD 8
__global__ __launch_bounds__(64)
void recur_kernel(const bf16* __restrict__ PKb, const float* __restrict__ PKw,
                  const float* __restrict__ PKs, float* __restrict__ Y) {
  int blk = blockIdx.x;
  int bh = blk & 63, sib = blk >> 6;
  int b = bh >> 4, h = bh & 15;
  int lane = threadIdx.x;
  int jq = lane & 15, j0 = jq * 4;
  int rl = lane >> 4;
  int i = sib * 4 + rl;

  const unsigned short* pb =
      (const unsigned short*)(PKb) + ((size_t)b * 1024 * 16 + h) * 320;
  const float* pw = PKw + (size_t)b * 1024 * 1024 + h * 64;
  const float* ps = PKs + (size_t)b * 32768 + h * 2;
  float* yout = Y + (size_t)b * 1024 * 1024 + h * 64 + i;

  uint2 Lr[RD], Lk[RD], La[RD], Lb[RD];
  float4 Lw[RD];
  float2 Ls[RD];
  unsigned short Lv[RD];

#pragma unroll
  for (int d = 0; d < RD; ++d) {
    const unsigned short* s = pb + (size_t)d * 5120;
    Lr[d] = *(const uint2*)(s + j0);
    Lk[d] = *(const uint2*)(s + 64 + j0);
    La[d] = *(const uint2*)(s + 192 + j0);
    Lb[d] = *(const uint2*)(s + 256 + j0);
    Lv[d] = s[128 + i];
    Lw[d] = *(const float4*)(pw + (size_t)d * 1024 + j0);
    Ls[d] = *(const float2*)(ps + (size_t)d * 32);
  }

  float S0 = 0.f, S1 = 0.f, S2 = 0.f, S3 = 0.f;

  for (int t0 = 0; t0 < 1024; t0 += RD) {
#pragma unroll
    for (int d = 0; d < RD; ++d) {
      int t = t0 + d;
      uint2 ur = Lr[d], uk = Lk[d], ua = La[d], ub = Lb[d];
      float4 wv = Lw[d];
      float2 sc = Ls[d];
      float vi = bfbits2f(Lv[d]);
      {  // prefetch step t+RD into slot d (overread past end is benign)
        size_t tn = (size_t)(t + RD);
        const unsigned short* s = pb + tn * 5120;
        Lr[d] = *(const uint2*)(s + j0);
        Lk[d] = *(const uint2*)(s + 64 + j0);
        La[d] = *(const uint2*)(s + 192 + j0);
        Lb[d] = *(const uint2*)(s + 256 + j0);
        Lv[d] = s[128 + i];
        Lw[d] = *(const float4*)(pw + tn * 1024 + j0);
        Ls[d] = *(const float2*)(ps + tn * 32);
      }
      float ax = bfbits2f((unsigned short)(ua.x & 0xffffu)), ay = bfbits2f((unsigned short)(ua.x >> 16));
      float az = bfbits2f((unsigned short)(ua.y & 0xffffu)), aw = bfbits2f((unsigned short)(ua.y >> 16));
      float kx = bfbits2f((unsigned short)(uk.x & 0xffffu)), ky = bfbits2f((unsigned short)(uk.x >> 16));
      float kz = bfbits2f((unsigned short)(uk.y & 0xffffu)), kw = bfbits2f((unsigned short)(uk.y >> 16));
      float bx = bfbits2f((unsigned short)(ub.x & 0xffffu)), by = bfbits2f((unsigned short)(ub.x >> 16));
      float bz = bfbits2f((unsigned short)(ub.y & 0xffffu)), bw = bfbits2f((unsigned short)(ub.y >> 16));
      float rx = bfbits2f((unsigned short)(ur.x & 0xffffu)), ry = bfbits2f((unsigned short)(ur.x >> 16));
      float rz = bfbits2f((unsigned short)(ur.y & 0xffffu)), rw = bfbits2f((unsigned short)(ur.y >> 16));

      float p = (S0 * ax + S1 * ay) + (S2 * az + S3 * aw);
      float q = (S0 * (wv.x * rx) + S1 * (wv.y * ry)) + (S2 * (wv.z * rz) + S3 * (wv.w * rw));
      rowsum16x2(p, q);
      float y = q + p * sc.y + vi * sc.x;
      S0 = S0 * wv.x + (p * bx + vi * kx);
      S1 = S1 * wv.y + (p * by + vi * ky);
      S2 = S2 * wv.z + (p * bz + vi * kz);
      S3 = S3 * wv.w + (p * bw + vi * kw);
      if (jq == 0) yout[(size_t)t * 1024] = y;
    }
  }
}

// ---------------- GroupNorm + residual + g gate ----------------
__global__ __launch_bounds__(256)
void gn_kernel(const float* __restrict__ Y, const bf16* __restrict__ PKb,
               const float* __restrict__ G,
               const void* __restrict__ gw, const void* __restrict__ gb,
               const void* __restrict__ rk, const int* __restrict__ flag,
               bf16* __restrict__ Z)
{
  int fl = *flag;
  int slot = blockIdx.x * 4 + (threadIdx.x >> 6);
  int tg = slot >> 4, h = slot & 15;
  int n = threadIdx.x & 63, c = h * 64 + n;
  size_t pb = (size_t)tg * 5120 + (size_t)h * 320;
  float y = Y[(size_t)tg * 1024 + c];
  float rr = b2f(PKb[pb + n]), kf = b2f(PKb[pb + 64 + n]), vv = b2f(PKb[pb + 128 + n]);
  float s1 = y, s2 = y * y, s3 = rr * kf * ldin(rk, c, fl);
#pragma unroll
  for (int m = 1; m < 64; m <<= 1) {
    s1 += __shfl_xor(s1, m);
    s2 += __shfl_xor(s2, m);
    s3 += __shfl_xor(s3, m);
  }
  float mu = s1 * 0.015625f;
  float var = s2 * 0.015625f - mu * mu;
  float xn = (y - mu) * rsqrtf(var + 0.00064f);
  float yn = xn * ldin(gw, c, fl) + ldin(gb, c, fl);
  yn += s3 * vv;
  Z[(size_t)tg * 1024 + c] = f2b(yn * G[(size_t)tg * 1024 + c]);
}

// ---------------- final output GEMM ----------------
__global__ __launch_bounds__(256)
void outgemm_kernel(const bf16* Z, const bf16* cWo,
                    float* oF, bf16* oB, const int* __restrict__ flag)
{
  int fl = *flag;
  gemm_core(Z, cWo, 1024, 1024, blockIdx.x * 128, blockIdx.y * 128,
            [&](int row, int col, float f) {
    if (fl) oF[(size_t)row * 1024 + col] = f;
    else    oB[(size_t)row * 1024 + col] = f2b(f);
  });
}

extern "C" void kernel_launch(void* const* d_in, const int* in_sizes, int n_in,
                              void* d_out, int out_size, void* d_ws, size_t ws_size,
                              hipStream_t stream)
{
  const void* x      = d_in[0];
  const void* vfirst = d_in[1];
  const void* m_r = d_in[2];  const void* m_w = d_in[3];
  const void* m_k = d_in[4];  const void* m_v = d_in[5];
  const void* m_a = d_in[6];  const void* m_g = d_in[7];
  const void* w0  = d_in[8];  const void* w1  = d_in[9];  const void* w2  = d_in[10];
  const void* a0  = d_in[11]; const void* a1  = d_in[12]; const void* a2  = d_in[13];
  const void* v0p = d_in[14]; const void* v1  = d_in[15]; const void* v2  = d_in[16];
  const void* g1  = d_in[17]; const void* g2  = d_in[18];
  const void* k_k = d_in[19]; const void* k_a = d_in[20]; const void* r_k = d_in[21];
  const void* W_r = d_in[22]; const void* W_k = d_in[23];
  const void* W_v = d_in[24]; const void* W_o = d_in[25];
  const void* gnw = d_in[26]; const void* gnb = d_in[27];
  (void)in_sizes; (void)n_in; (void)out_size; (void)ws_size;

  char* ws = (char*)d_ws;
  size_t off = 0;
  auto alloc = [&](size_t bytes) -> void* {
    void* p = ws + off; off += (bytes + 255) & ~(size_t)255; return p;
  };
  const size_t BTC2 = (size_t)4096 * 1024 * 2;
  int*  flag = (int*)alloc(256);
  bf16* cWr = (bf16*)alloc((size_t)1048576 * 2);
  bf16* cWk = (bf16*)alloc((size_t)1048576 * 2);
  bf16* cWv = (bf16*)alloc((size_t)1048576 * 2);
  bf16* cWo = (bf16*)alloc((size_t)1048576 * 2);
  bf16* w1t = (bf16*)alloc((size_t)65536 * 2);
  bf16* w2t = (bf16*)alloc((size_t)65536 * 2);
  bf16* a1t = (bf16*)alloc((size_t)65536 * 2);
  bf16* a2t = (bf16*)alloc((size_t)65536 * 2);
  bf16* v1t = (bf16*)alloc((size_t)32768 * 2);
  bf16* v2t = (bf16*)alloc((size_t)32768 * 2);
  bf16* g1t = (bf16*)alloc((size_t)163840 * 2);
  bf16* g2t = (bf16*)alloc((size_t)163840 * 2);
  bf16* xr = (bf16*)alloc(BTC2);
  bf16* xw = (bf16*)alloc(BTC2);
  bf16* xk = (bf16*)alloc(BTC2);
  bf16* xv = (bf16*)alloc(BTC2);
  bf16* xa = (bf16*)alloc(BTC2);
  bf16* xg = (bf16*)alloc(BTC2);
  bf16* PKb = (bf16*)alloc((size_t)4096 * 5120 * 2);   // [BT][H][5][64]
  float* PKw = (float*)alloc((size_t)4096 * 1024 * 4); // [BT][C] wdec
  float* PKs = (float*)alloc((size_t)4096 * 32 * 4);   // [BT][H][2] {k.r, b.r}
  bf16* hw  = (bf16*)alloc((size_t)4096 * 64 * 2);
  bf16* ha  = (bf16*)alloc((size_t)4096 * 64 * 2);
  bf16* hv  = (bf16*)alloc((size_t)4096 * 32 * 2);
  bf16* hg  = (bf16*)alloc((size_t)4096 * 160 * 2);
  // dead-buffer reuse (lifetimes verified by launch order):
  float* G = (float*)xr;   // over xr+xw; written by stage2 (after stage1/bigrkv consume)
  float* Y = (float*)xk;   // over xk+xv; written by recur
  bf16*  Z = xa;           // written by gn (after stage1 consumes xa)

  detect_kernel<<<1, 256, 0, stream>>>((const unsigned*)x, flag);
  prep_kernel<<<35328, 256, 0, stream>>>(
      x, m_r, m_w, m_k, m_v, m_a, m_g,
      W_r, W_k, W_v, W_o, cWr, cWk, cWv, cWo,
      w1, w2, a1, a2, v1, v2, g1, g2,
      w1t, w2t, a1t, a2t, v1t, v2t, g1t, g2t,
      flag, xr, xw, xk, xv, xa, xg);

  stage1_kernel<<<dim3(32, 5), 256, 0, stream>>>(xw, xa, xv, xg,
                                                 w1t, a1t, v1t, g1t, hw, ha, hv, hg);
  bigrkv_kernel<<<dim3(32, 8, 3), 256, 0, stream>>>(xr, xk, xv, cWr, cWk, cWv, PKb);
  stage2_kernel<<<dim3(32, 8, 4), 256, 0, stream>>>(hw, ha, hv, hg,
                                                    w2t, a2t, v2t, g2t,
                                                    PKb, PKw, G, w0, a0, v0p, vfirst, flag);
  post_kernel<<<16384, 256, 0, stream>>>(PKb, PKs, k_k, k_a, flag);
  recur_kernel<<<1024, 64, 0, stream>>>(PKb, PKw, PKs, Y);
  gn_kernel<<<16384, 256, 0, stream>>>(Y, PKb, G, gnw, gnb, r_k, flag, Z);
  outgemm_kernel<<<dim3(32, 8), 256, 0, stream>>>(Z, cWo, (float*)d_out, (bf16*)d_out, flag);
}

// Round 8
// 574.468 us; speedup vs baseline: 1.2561x; 1.1710x over previous
//
#include <hip/hip_runtime.h>
#include <hip/hip_bf16.h>
#include <math.h>

// RWKV-7 Tmix forward, B=4 T=1024 C=1024 H=16 N=64.
// R8: recurrence = R3 body (4 rows/wave, 1024 blocks, RD=8 ring, pure-DPP
// 16-lane reductions) with __launch_bounds__(64,1) so the scheduler's VGPR
// target (waves-per-eu=1 -> 512 regs) lets the prefetch ring stay register-
// resident instead of being sunk to uses (R3..R6 all show collapsed rings:
// VGPR 40-84 < ring size). Input dtype (f32 vs bf16) runtime-detected.

using bf16 = __hip_bfloat16;
typedef __attribute__((ext_vector_type(8))) short bf16x8;
typedef __attribute__((ext_vector_type(4))) float f32x4;

#define DEVINL __device__ __forceinline__

DEVINL float b2f(bf16 v) { return __bfloat162float(v); }
DEVINL bf16 f2b(float f) { return __float2bfloat16(f); }
DEVINL float sigm(float x) { return 1.f / (1.f + __expf(-x)); }
DEVINL float bfbits2f(unsigned short s) { return __uint_as_float(((unsigned)s) << 16); }
DEVINL float ldin(const void* p, size_t i, int fl) {
  return fl ? ((const float*)p)[i] : b2f(((const bf16*)p)[i]);
}

DEVINL void g2lds16(const void* g, void* l) {
  __builtin_amdgcn_global_load_lds(
      (__attribute__((address_space(1))) void*)(g),
      (__attribute__((address_space(3))) void*)(l), 16, 0, 0);
}

template<int CTRL>
DEVINL float dpp_add(float x) {
  int t = __builtin_amdgcn_update_dpp(0, __float_as_int(x), CTRL, 0xf, 0xf, true);
  return x + __int_as_float(t);
}
DEVINL float rowsum16(float x) {
  x = dpp_add<0x121>(x);  // row_ror:1
  x = dpp_add<0x122>(x);  // row_ror:2
  x = dpp_add<0x124>(x);  // row_ror:4
  x = dpp_add<0x128>(x);  // row_ror:8
  return x;
}

// ---------------- dtype probe: flag=1 -> inputs are f32 ----------------
__global__ void detect_kernel(const unsigned* __restrict__ x, int* __restrict__ flag) {
  __shared__ int cnt[4];
  int tid = threadIdx.x;
  unsigned w = x[tid];
  float v = fabsf(bfbits2f((unsigned short)(w & 0xffffu)));
  bool plaus = (v >= 1e-4f && v <= 16.f);
  unsigned long long m = __ballot(plaus);
  if ((tid & 63) == 0) cnt[tid >> 6] = __popcll(m);
  __syncthreads();
  if (tid == 0) *flag = (cnt[0] + cnt[1] + cnt[2] + cnt[3] < 128) ? 1 : 0;
}

// ---------------- prep: mix + big-weight cvt + 8 small transposes ----------------
__global__ __launch_bounds__(256)
void prep_kernel(const void* __restrict__ x,
    const void* mr, const void* mw, const void* mk,
    const void* mv, const void* ma, const void* mg,
    const void* W_r, const void* W_k, const void* W_v, const void* W_o,
    bf16* cWr, bf16* cWk, bf16* cWv, bf16* cWo,
    const void* w1, const void* w2, const void* a1, const void* a2,
    const void* v1, const void* v2, const void* g1, const void* g2,
    bf16* w1t, bf16* w2t, bf16* a1t, bf16* a2t,
    bf16* v1t, bf16* v2t, bf16* g1t, bf16* g2t,
    const int* __restrict__ flag,
    bf16* oxr, bf16* oxw, bf16* oxk, bf16* oxv, bf16* oxa, bf16* oxg)
{
  int fl = *flag;
  int bx = blockIdx.x;
  if (bx < 16384) {                       // token-shift mix over 4M
    size_t idx = (size_t)bx * 256 + threadIdx.x;
    int c = (int)(idx & 1023);
    int t = (int)((idx >> 10) & 1023);
    float xc = ldin(x, idx, fl);
    float px = (t == 0) ? 0.f : ldin(x, idx - 1024, fl);
    float dx = px - xc;
    oxr[idx] = f2b(xc + ldin(mr, c, fl) * dx);
    oxw[idx] = f2b(xc + ldin(mw, c, fl) * dx);
    oxk[idx] = f2b(xc + ldin(mk, c, fl) * dx);
    oxv[idx] = f2b(xc + ldin(mv, c, fl) * dx);
    oxa[idx] = f2b(xc + ldin(ma, c, fl) * dx);
    oxg[idx] = f2b(xc + ldin(mg, c, fl) * dx);
  } else if (bx < 32768) {                // big-weight convert, 4 x 1M
    int g = (bx - 16384) * 256 + threadIdx.x;
    int seg = g >> 20, i = g & 1048575;
    const void* s = seg == 0 ? W_r : seg == 1 ? W_k : seg == 2 ? W_v : W_o;
    bf16* d = seg == 0 ? cWr : seg == 1 ? cWk : seg == 2 ? cWv : cWo;
    d[i] = fl ? f2b(((const float*)s)[i]) : ((const bf16*)s)[i];
  } else {                                // 8 small transposes [K,N]->[N,K]
    int idx = (bx - 32768) * 256 + threadIdx.x;
    if (idx >= 655360) return;
    const int ends[8] = {65536, 131072, 196608, 262144, 294912, 327680, 491520, 655360};
    const int Ks[8] = {1024, 64, 1024, 64, 1024, 32, 1024, 160};
    const int Nd[8] = {64, 1024, 64, 1024, 32, 1024, 160, 1024};
    const void* srcs[8] = {w1, w2, a1, a2, v1, v2, g1, g2};
    bf16* dsts[8] = {w1t, w2t, a1t, a2t, v1t, v2t, g1t, g2t};
    int seg = 0, start = 0;
#pragma unroll
    for (int s2 = 0; s2 < 7; s2++)
      if (idx >= ends[s2]) { seg = s2 + 1; start = ends[s2]; }
    int local = idx - start;
    int K = Ks[seg], N = Nd[seg];
    int k = local / N, n = local - k * N;
    dsts[seg][(size_t)n * K + k] = f2b(ldin(srcs[seg], local, fl));
  }
}

// ---------------- shared MFMA GEMM core: C[M,N] = A[M,K] * B[N,K]^T ----------------
template<typename Epi>
DEVINL void gemm_core(const bf16* __restrict__ A, const bf16* __restrict__ Bt,
                      int K, int Brows, int m0, int n0, Epi&& epi)
{
  __shared__ short As[128 * 32];
  __shared__ short Bs[128 * 32];
  const int tid = threadIdx.x;
  const int wid = tid >> 6, lane = tid & 63;
  const int wr = (wid >> 1) * 64, wc = (wid & 1) * 64;

  f32x4 acc[4][4] = {};

  const int lrow = lane >> 2;
  const int lcol = (lane & 3) * 8;
  int arow0 = m0 + (wid * 2 + 0) * 16 + lrow;
  int arow1 = m0 + (wid * 2 + 1) * 16 + lrow;
  int brow0 = n0 + (wid * 2 + 0) * 16 + lrow; if (brow0 >= Brows) brow0 = Brows - 1;
  int brow1 = n0 + (wid * 2 + 1) * 16 + lrow; if (brow1 >= Brows) brow1 = Brows - 1;

  const short* Ag = (const short*)A;
  const short* Bg = (const short*)Bt;

  for (int kk = 0; kk < K; kk += 32) {
    __syncthreads();
    g2lds16(Ag + (size_t)arow0 * K + kk + lcol, As + (wid * 2 + 0) * 512);
    g2lds16(Ag + (size_t)arow1 * K + kk + lcol, As + (wid * 2 + 1) * 512);
    g2lds16(Bg + (size_t)brow0 * K + kk + lcol, Bs + (wid * 2 + 0) * 512);
    g2lds16(Bg + (size_t)brow1 * K + kk + lcol, Bs + (wid * 2 + 1) * 512);
    __syncthreads();
    bf16x8 af[4], bfr[4];
#pragma unroll
    for (int mi = 0; mi < 4; mi++)
      af[mi] = *(const bf16x8*)(As + (wr + mi * 16 + (lane & 15)) * 32 + (lane >> 4) * 8);
#pragma unroll
    for (int ni = 0; ni < 4; ni++)
      bfr[ni] = *(const bf16x8*)(Bs + (wc + ni * 16 + (lane & 15)) * 32 + (lane >> 4) * 8);
#pragma unroll
    for (int mi = 0; mi < 4; mi++)
#pragma unroll
      for (int ni = 0; ni < 4; ni++)
        acc[mi][ni] = __builtin_amdgcn_mfma_f32_16x16x32_bf16(af[mi], bfr[ni], acc[mi][ni], 0, 0, 0);
  }

  const int cl0 = lane & 15, r0 = (lane >> 4) * 4;
#pragma unroll
  for (int mi = 0; mi < 4; mi++)
#pragma unroll
    for (int ni = 0; ni < 4; ni++) {
      int col = n0 + wc + ni * 16 + cl0;
#pragma unroll
      for (int rr = 0; rr < 4; rr++)
        epi(m0 + wr + mi * 16 + r0 + rr, col, acc[mi][ni][rr]);
    }
}

// ---------------- stage1: xw@w1 tanh | xa@a1 | xv@v1 | xg@g1 sigm ----------------
__global__ __launch_bounds__(256)
void stage1_kernel(const bf16* xw, const bf16* xa, const bf16* xv, const bf16* xg,
                   const bf16* w1t, const bf16* a1t, const bf16* v1t, const bf16* g1t,
                   bf16* hw, bf16* ha, bf16* hv, bf16* hg)
{
  int y = blockIdx.y;
  int seg = (y <= 2) ? y : 3;
  int n0 = (y == 4) ? 128 : 0;
  const bf16* A  = seg == 0 ? xw  : seg == 1 ? xa  : seg == 2 ? xv  : xg;
  const bf16* Bt = seg == 0 ? w1t : seg == 1 ? a1t : seg == 2 ? v1t : g1t;
  int NS         = seg == 0 ? 64  : seg == 1 ? 64  : seg == 2 ? 32  : 160;
  bf16* out      = seg == 0 ? hw  : seg == 1 ? ha  : seg == 2 ? hv  : hg;
  gemm_core(A, Bt, 1024, NS, blockIdx.x * 128, n0, [&](int row, int col, float f) {
    if (col >= NS) return;
    if (seg == 0) f = tanhf(f);
    else if (seg == 3) f = sigm(f);
    out[(size_t)row * NS + col] = f2b(f);
  });
}

// ---------------- big r/k/v projections -> PKb slots 0/1/2 ----------------
// PKb slots: 0=r 1=kraw->kfinal 2=v 3=asig->kkn 4=b
__global__ __launch_bounds__(256)
void bigrkv_kernel(const bf16* xr, const bf16* xk, const bf16* xv,
                   const bf16* cWr, const bf16* cWk, const bf16* cWv,
                   bf16* __restrict__ PKb)
{
  int z = blockIdx.z;
  const bf16* A  = z == 0 ? xr  : z == 1 ? xk  : xv;
  const bf16* Bt = z == 0 ? cWr : z == 1 ? cWk : cWv;
  gemm_core(A, Bt, 1024, 1024, blockIdx.x * 128, blockIdx.y * 128,
            [&](int row, int col, float f) {
    PKb[(size_t)row * 5120 + (col >> 6) * 320 + z * 64 + (col & 63)] = f2b(f);
  });
}

// ---------------- stage2: wdec->PKw | asig->slot3 | vblend->slot2 | G ----------------
__global__ __launch_bounds__(256)
void stage2_kernel(const bf16* hw, const bf16* ha, const bf16* hv, const bf16* hg,
                   const bf16* w2t, const bf16* a2t, const bf16* v2t, const bf16* g2t,
                   bf16* __restrict__ PKb, float* __restrict__ PKw, float* __restrict__ G,
                   const void* w0, const void* a0, const void* v0p, const void* vfirst,
                   const int* __restrict__ flag)
{
  int fl = *flag;
  int z = blockIdx.z;
  const bf16* A  = z == 0 ? hw  : z == 1 ? ha  : z == 2 ? hv  : hg;
  const bf16* Bt = z == 0 ? w2t : z == 1 ? a2t : z == 2 ? v2t : g2t;
  int K          = z == 0 ? 64  : z == 1 ? 64  : z == 2 ? 32  : 160;
  gemm_core(A, Bt, K, 1024, blockIdx.x * 128, blockIdx.y * 128,
            [&](int row, int col, float f) {
    if (z == 0) {
      float zz = -(ldin(w0, col, fl) + f);
      float sp = fmaxf(zz, 0.f) + __logf(1.f + __expf(-fabsf(zz)));
      PKw[(size_t)row * 1024 + col] = __expf(-__expf(-sp - 0.5f));
    } else if (z == 1) {
      PKb[(size_t)row * 5120 + (col >> 6) * 320 + 192 + (col & 63)] =
          f2b(sigm(ldin(a0, col, fl) + f));
    } else if (z == 2) {
      float sg = sigm(ldin(v0p, col, fl) + f);
      size_t pa = (size_t)row * 5120 + (col >> 6) * 320 + 128 + (col & 63);
      float vr = b2f(PKb[pa]);
      float vf = ldin(vfirst, (size_t)row * 1024 + col, fl);
      PKb[pa] = f2b(vr + (vf - vr) * sg);
    } else {
      G[(size_t)row * 1024 + col] = f;
    }
  });
}

// ---------------- per-(t,h) finalize: kkn, b, k_final ----------------
// PKb slots: 0=r 1=kraw->kfinal 2=v 3=asig->kkn 4=b
__global__ __launch_bounds__(256)
void post_kernel(bf16* __restrict__ PKb, const void* __restrict__ kkw,
                 const void* __restrict__ kaw, const int* __restrict__ flag) {
  int fl = *flag;
  int slot = blockIdx.x * 4 + (threadIdx.x >> 6);
  int tg = slot >> 4, h = slot & 15;
  int n = threadIdx.x & 63, c = h * 64 + n;
  size_t pb = (size_t)tg * 5120 + (size_t)h * 320;
  float kraw = b2f(PKb[pb + 64 + n]);
  float asig = b2f(PKb[pb + 192 + n]);
  float kk = kraw * ldin(kkw, c, fl);
  float ss = kk * kk;
  ss += __shfl_xor(ss, 1);  ss += __shfl_xor(ss, 2);  ss += __shfl_xor(ss, 4);
  ss += __shfl_xor(ss, 8);  ss += __shfl_xor(ss, 16); ss += __shfl_xor(ss, 32);
  float kkn = kk / fmaxf(sqrtf(ss), 1e-12f);
  PKb[pb + 192 + n] = f2b(kkn);
  PKb[pb + 256 + n] = f2b(-kkn * asig);
  PKb[pb + 64 + n]  = f2b(kraw * (1.f + (asig - 1.f) * ldin(kaw, c, fl)));
}

// ---------------- sequential recurrence: R3 body + waves-per-eu=1 ----------------
// 1024 blocks x 64 thr. blk = sib*64 + bh (16 sibs per bh, same XCD).
// Wave owns rows [sib*4, sib*4+4); lane: rl=lane>>4 (row), jq=lane&15 (4 j's).
// No LDS, no barriers. RD-deep register prefetch; pure-DPP 16-lane reductions.
// __launch_bounds__(64,1): waves-per-eu=1 -> 512-VGPR budget so the scheduler
// keeps the ring in registers instead of sinking loads to uses (the R3..R6
// ring-collapse: VGPR 40-84 < ring footprint, exposing ~300cyc L2 per step).
// Overreads <=8 steps past PKb (lands in PKw) and PKw (lands in hw) - benign.
#define RD 8
__global__ __launch_bounds__(64, 1)
void recur_kernel(const bf16* __restrict__ PKb, const float* __restrict__ PKw,
                  float* __restrict__ Y) {
  int blk = blockIdx.x;
  int bh = blk & 63, sib = blk >> 6;
  int b = bh >> 4, h = bh & 15;
  int lane = threadIdx.x;
  int jq = lane & 15, j0 = jq * 4;
  int rl = lane >> 4;
  int i = sib * 4 + rl;

  const unsigned short* pb =
      (const unsigned short*)(PKb) + ((size_t)b * 1024 * 16 + h) * 320;
  const float* pw = PKw + (size_t)b * 1024 * 1024 + h * 64;
  float* yout = Y + (size_t)b * 1024 * 1024 + h * 64 + i;

  uint2 Lr[RD], Lk[RD], La[RD], Lb[RD];
  float4 Lw[RD];
  unsigned short Lv[RD];

#pragma unroll
  for (int d = 0; d < RD; ++d) {
    const unsigned short* s = pb + (size_t)d * 5120;
    Lr[d] = *(const uint2*)(s + j0);
    Lk[d] = *(const uint2*)(s + 64 + j0);
    La[d] = *(const uint2*)(s + 192 + j0);
    Lb[d] = *(const uint2*)(s + 256 + j0);
    Lv[d] = s[128 + i];
    Lw[d] = *(const float4*)(pw + (size_t)d * 1024 + j0);
  }

  float S0 = 0.f, S1 = 0.f, S2 = 0.f, S3 = 0.f;

  for (int t0 = 0; t0 < 1024; t0 += RD) {
#pragma unroll
    for (int d = 0; d < RD; ++d) {
      int t = t0 + d;
      uint2 ur = Lr[d], uk = Lk[d], ua = La[d], ub = Lb[d];
      float4 wv = Lw[d];
      float vi = bfbits2f(Lv[d]);
      {  // prefetch step t+RD into slot d (overread past end is benign)
        const unsigned short* s = pb + (size_t)(t + RD) * 5120;
        Lr[d] = *(const uint2*)(s + j0);
        Lk[d] = *(const uint2*)(s + 64 + j0);
        La[d] = *(const uint2*)(s + 192 + j0);
        Lb[d] = *(const uint2*)(s + 256 + j0);
        Lv[d] = s[128 + i];
        Lw[d] = *(const float4*)(pw + (size_t)(t + RD) * 1024 + j0);
      }
      float ax = bfbits2f((unsigned short)(ua.x & 0xffffu)), ay = bfbits2f((unsigned short)(ua.x >> 16));
      float az = bfbits2f((unsigned short)(ua.y & 0xffffu)), aw = bfbits2f((unsigned short)(ua.y >> 16));
      float kx = bfbits2f((unsigned short)(uk.x & 0xffffu)), ky = bfbits2f((unsigned short)(uk.x >> 16));
      float kz = bfbits2f((unsigned short)(uk.y & 0xffffu)), kw = bfbits2f((unsigned short)(uk.y >> 16));
      float bx = bfbits2f((unsigned short)(ub.x & 0xffffu)), by = bfbits2f((unsigned short)(ub.x >> 16));
      float bz = bfbits2f((unsigned short)(ub.y & 0xffffu)), bw = bfbits2f((unsigned short)(ub.y >> 16));
      float rx = bfbits2f((unsigned short)(ur.x & 0xffffu)), ry = bfbits2f((unsigned short)(ur.x >> 16));
      float rz = bfbits2f((unsigned short)(ur.y & 0xffffu)), rw = bfbits2f((unsigned short)(ur.y >> 16));

      float sa = (S0 * ax + S1 * ay) + (S2 * az + S3 * aw);
      sa = rowsum16(sa);
      S0 = S0 * wv.x + (sa * bx + vi * kx);
      S1 = S1 * wv.y + (sa * by + vi * ky);
      S2 = S2 * wv.z + (sa * bz + vi * kz);
      S3 = S3 * wv.w + (sa * bw + vi * kw);
      float y = (S0 * rx + S1 * ry) + (S2 * rz + S3 * rw);
      y = rowsum16(y);
      if (jq == 0) yout[(size_t)t * 1024] = y;
    }
  }
}

// ---------------- GroupNorm + residual + g gate ----------------
__global__ __launch_bounds__(256)
void gn_kernel(const float* __restrict__ Y, const bf16* __restrict__ PKb,
               const float* __restrict__ G,
               const void* __restrict__ gw, const void* __restrict__ gb,
               const void* __restrict__ rk, const int* __restrict__ flag,
               bf16* __restrict__ Z)
{
  int fl = *flag;
  int slot = blockIdx.x * 4 + (threadIdx.x >> 6);
  int tg = slot >> 4, h = slot & 15;
  int n = threadIdx.x & 63, c = h * 64 + n;
  size_t pb = (size_t)tg * 5120 + (size_t)h * 320;
  float y = Y[(size_t)tg * 1024 + c];
  float rr = b2f(PKb[pb + n]), kf = b2f(PKb[pb + 64 + n]), vv = b2f(PKb[pb + 128 + n]);
  float s1 = y, s2 = y * y, s3 = rr * kf * ldin(rk, c, fl);
#pragma unroll
  for (int m = 1; m < 64; m <<= 1) {
    s1 += __shfl_xor(s1, m);
    s2 += __shfl_xor(s2, m);
    s3 += __shfl_xor(s3, m);
  }
  float mu = s1 * 0.015625f;
  float var = s2 * 0.015625f - mu * mu;
  float xn = (y - mu) * rsqrtf(var + 0.00064f);
  float yn = xn * ldin(gw, c, fl) + ldin(gb, c, fl);
  yn += s3 * vv;
  Z[(size_t)tg * 1024 + c] = f2b(yn * G[(size_t)tg * 1024 + c]);
}

// ---------------- final output GEMM ----------------
__global__ __launch_bounds__(256)
void outgemm_kernel(const bf16* Z, const bf16* cWo,
                    float* oF, bf16* oB, const int* __restrict__ flag)
{
  int fl = *flag;
  gemm_core(Z, cWo, 1024, 1024, blockIdx.x * 128, blockIdx.y * 128,
            [&](int row, int col, float f) {
    if (fl) oF[(size_t)row * 1024 + col] = f;
    else    oB[(size_t)row * 1024 + col] = f2b(f);
  });
}

extern "C" void kernel_launch(void* const* d_in, const int* in_sizes, int n_in,
                              void* d_out, int out_size, void* d_ws, size_t ws_size,
                              hipStream_t stream)
{
  const void* x      = d_in[0];
  const void* vfirst = d_in[1];
  const void* m_r = d_in[2];  const void* m_w = d_in[3];
  const void* m_k = d_in[4];  const void* m_v = d_in[5];
  const void* m_a = d_in[6];  const void* m_g = d_in[7];
  const void* w0  = d_in[8];  const void* w1  = d_in[9];  const void* w2  = d_in[10];
  const void* a0  = d_in[11]; const void* a1  = d_in[12]; const void* a2  = d_in[13];
  const void* v0p = d_in[14]; const void* v1  = d_in[15]; const void* v2  = d_in[16];
  const void* g1  = d_in[17]; const void* g2  = d_in[18];
  const void* k_k = d_in[19]; const void* k_a = d_in[20]; const void* r_k = d_in[21];
  const void* W_r = d_in[22]; const void* W_k = d_in[23];
  const void* W_v = d_in[24]; const void* W_o = d_in[25];
  const void* gnw = d_in[26]; const void* gnb = d_in[27];
  (void)in_sizes; (void)n_in; (void)out_size; (void)ws_size;

  char* ws = (char*)d_ws;
  size_t off = 0;
  auto alloc = [&](size_t bytes) -> void* {
    void* p = ws + off; off += (bytes + 255) & ~(size_t)255; return p;
  };
  const size_t BTC2 = (size_t)4096 * 1024 * 2;
  int*  flag = (int*)alloc(256);
  bf16* cWr = (bf16*)alloc((size_t)1048576 * 2);
  bf16* cWk = (bf16*)alloc((size_t)1048576 * 2);
  bf16* cWv = (bf16*)alloc((size_t)1048576 * 2);
  bf16* cWo = (bf16*)alloc((size_t)1048576 * 2);
  bf16* w1t = (bf16*)alloc((size_t)65536 * 2);
  bf16* w2t = (bf16*)alloc((size_t)65536 * 2);
  bf16* a1t = (bf16*)alloc((size_t)65536 * 2);
  bf16* a2t = (bf16*)alloc((size_t)65536 * 2);
  bf16* v1t = (bf16*)alloc((size_t)32768 * 2);
  bf16* v2t = (bf16*)alloc((size_t)32768 * 2);
  bf16* g1t = (bf16*)alloc((size_t)163840 * 2);
  bf16* g2t = (bf16*)alloc((size_t)163840 * 2);
  bf16* xr = (bf16*)alloc(BTC2);
  bf16* xw = (bf16*)alloc(BTC2);
  bf16* xk = (bf16*)alloc(BTC2);
  bf16* xv = (bf16*)alloc(BTC2);
  bf16* xa = (bf16*)alloc(BTC2);
  bf16* xg = (bf16*)alloc(BTC2);
  bf16* PKb = (bf16*)alloc((size_t)4096 * 5120 * 2);   // [BT][H][5][64]
  float* PKw = (float*)alloc((size_t)4096 * 1024 * 4); // [BT][C] wdec
  bf16* hw  = (bf16*)alloc((size_t)4096 * 64 * 2);
  bf16* ha  = (bf16*)alloc((size_t)4096 * 64 * 2);
  bf16* hv  = (bf16*)alloc((size_t)4096 * 32 * 2);
  bf16* hg  = (bf16*)alloc((size_t)4096 * 160 * 2);
  // dead-buffer reuse (lifetimes verified by launch order):
  float* G = (float*)xr;   // over xr+xw; written by stage2 (after stage1/bigrkv consume)
  float* Y = (float*)xk;   // over xk+xv; written by recur
  bf16*  Z = xa;           // written by gn (after stage1 consumes xa)

  detect_kernel<<<1, 256, 0, stream>>>((const unsigned*)x, flag);
  prep_kernel<<<35328, 256, 0, stream>>>(
      x, m_r, m_w, m_k, m_v, m_a, m_g,
      W_r, W_k, W_v, W_o, cWr, cWk, cWv, cWo,
      w1, w2, a1, a2, v1, v2, g1, g2,
      w1t, w2t, a1t, a2t, v1t, v2t, g1t, g2t,
      flag, xr, xw, xk, xv, xa, xg);

  stage1_kernel<<<dim3(32, 5), 256, 0, stream>>>(xw, xa, xv, xg,
                                                 w1t, a1t, v1t, g1t, hw, ha, hv, hg);
  bigrkv_kernel<<<dim3(32, 8, 3), 256, 0, stream>>>(xr, xk, xv, cWr, cWk, cWv, PKb);
  stage2_kernel<<<dim3(32, 8, 4), 256, 0, stream>>>(hw, ha, hv, hg,
                                                    w2t, a2t, v2t, g2t,
                                                    PKb, PKw, G, w0, a0, v0p, vfirst, flag);
  post_kernel<<<16384, 256, 0, stream>>>(PKb, k_k, k_a, flag);
  recur_kernel<<<1024, 64, 0, stream>>>(PKb, PKw, Y);
  gn_kernel<<<16384, 256, 0, stream>>>(Y, PKb, G, gnw, gnb, r_k, flag, Z);
  outgemm_kernel<<<dim3(32, 8), 256, 0, stream>>>(Z, cWo, (float*)d_out, (bf16*)d_out, flag);
}

// Round 10
// 571.671 us; speedup vs baseline: 1.2622x; 1.0049x over previous
//
#include <hip/hip_runtime.h>
#include <hip/hip_bf16.h>
#include <math.h>

// RWKV-7 Tmix forward, B=4 T=1024 C=1024 H=16 N=64.
// R10: R9 (LDS double-buffered recurrence ring via global_load_lds, packed
// 1024B/step records) + the missing explicit s_waitcnt vmcnt(8) between
// prefetch-issue and current-buffer ds_reads (single-wave block has no
// barrier, so the compiler emits no drain -> R9's race).
// Input dtype (f32 vs bf16) runtime-detected.

using bf16 = __hip_bfloat16;
typedef __attribute__((ext_vector_type(8))) short bf16x8;
typedef __attribute__((ext_vector_type(4))) float f32x4;

#define DEVINL __device__ __forceinline__

DEVINL float b2f(bf16 v) { return __bfloat162float(v); }
DEVINL bf16 f2b(float f) { return __float2bfloat16(f); }
DEVINL float sigm(float x) { return 1.f / (1.f + __expf(-x)); }
DEVINL float bfbits2f(unsigned short s) { return __uint_as_float(((unsigned)s) << 16); }
DEVINL float lo16(unsigned u) { return __uint_as_float(u << 16); }
DEVINL float hi16(unsigned u) { return __uint_as_float(u & 0xffff0000u); }
DEVINL float ldin(const void* p, size_t i, int fl) {
  return fl ? ((const float*)p)[i] : b2f(((const bf16*)p)[i]);
}

DEVINL void g2lds16(const void* g, void* l) {
  __builtin_amdgcn_global_load_lds(
      (__attribute__((address_space(1))) void*)(g),
      (__attribute__((address_space(3))) void*)(l), 16, 0, 0);
}

// wait until at most 8 vmem ops outstanding (drains all older ops);
// memory-clobber fences pin ds_read ordering around it.
DEVINL void wait_vmcnt8() {
  __asm__ volatile("" ::: "memory");
  __builtin_amdgcn_s_waitcnt(0x0F78);   // lgkmcnt=15 expcnt=7 vmcnt=8
  __asm__ volatile("" ::: "memory");
}

template<int CTRL>
DEVINL float dpp_add(float x) {
  int t = __builtin_amdgcn_update_dpp(0, __float_as_int(x), CTRL, 0xf, 0xf, true);
  return x + __int_as_float(t);
}
DEVINL float rowsum16(float x) {
  x = dpp_add<0x121>(x);  // row_ror:1
  x = dpp_add<0x122>(x);  // row_ror:2
  x = dpp_add<0x124>(x);  // row_ror:4
  x = dpp_add<0x128>(x);  // row_ror:8
  return x;
}

// Packed stream addressing (shorts): step base = ((b*16+h)*1024 + t)*512
// [0,256): j*4 + slot (0=r 1=k 2=a 3=b)  [256,320): v[n]  floats [160,224): w[n]
DEVINL size_t stream_sb(int row, int h) {
  return ((size_t)((row >> 10) * 16 + h) * 1024 + (row & 1023)) * 512;
}

// ---------------- dtype probe: flag=1 -> inputs are f32 ----------------
__global__ void detect_kernel(const unsigned* __restrict__ x, int* __restrict__ flag) {
  __shared__ int cnt[4];
  int tid = threadIdx.x;
  unsigned w = x[tid];
  float v = fabsf(bfbits2f((unsigned short)(w & 0xffffu)));
  bool plaus = (v >= 1e-4f && v <= 16.f);
  unsigned long long m = __ballot(plaus);
  if ((tid & 63) == 0) cnt[tid >> 6] = __popcll(m);
  __syncthreads();
  if (tid == 0) *flag = (cnt[0] + cnt[1] + cnt[2] + cnt[3] < 128) ? 1 : 0;
}

// ---------------- prep: mix + big-weight cvt + 8 small transposes ----------------
__global__ __launch_bounds__(256)
void prep_kernel(const void* __restrict__ x,
    const void* mr, const void* mw, const void* mk,
    const void* mv, const void* ma, const void* mg,
    const void* W_r, const void* W_k, const void* W_v, const void* W_o,
    bf16* cWr, bf16* cWk, bf16* cWv, bf16* cWo,
    const void* w1, const void* w2, const void* a1, const void* a2,
    const void* v1, const void* v2, const void* g1, const void* g2,
    bf16* w1t, bf16* w2t, bf16* a1t, bf16* a2t,
    bf16* v1t, bf16* v2t, bf16* g1t, bf16* g2t,
    const int* __restrict__ flag,
    bf16* oxr, bf16* oxw, bf16* oxk, bf16* oxv, bf16* oxa, bf16* oxg)
{
  int fl = *flag;
  int bx = blockIdx.x;
  if (bx < 16384) {                       // token-shift mix over 4M
    size_t idx = (size_t)bx * 256 + threadIdx.x;
    int c = (int)(idx & 1023);
    int t = (int)((idx >> 10) & 1023);
    float xc = ldin(x, idx, fl);
    float px = (t == 0) ? 0.f : ldin(x, idx - 1024, fl);
    float dx = px - xc;
    oxr[idx] = f2b(xc + ldin(mr, c, fl) * dx);
    oxw[idx] = f2b(xc + ldin(mw, c, fl) * dx);
    oxk[idx] = f2b(xc + ldin(mk, c, fl) * dx);
    oxv[idx] = f2b(xc + ldin(mv, c, fl) * dx);
    oxa[idx] = f2b(xc + ldin(ma, c, fl) * dx);
    oxg[idx] = f2b(xc + ldin(mg, c, fl) * dx);
  } else if (bx < 32768) {                // big-weight convert, 4 x 1M
    int g = (bx - 16384) * 256 + threadIdx.x;
    int seg = g >> 20, i = g & 1048575;
    const void* s = seg == 0 ? W_r : seg == 1 ? W_k : seg == 2 ? W_v : W_o;
    bf16* d = seg == 0 ? cWr : seg == 1 ? cWk : seg == 2 ? cWv : cWo;
    d[i] = fl ? f2b(((const float*)s)[i]) : ((const bf16*)s)[i];
  } else {                                // 8 small transposes [K,N]->[N,K]
    int idx = (bx - 32768) * 256 + threadIdx.x;
    if (idx >= 655360) return;
    const int ends[8] = {65536, 131072, 196608, 262144, 294912, 327680, 491520, 655360};
    const int Ks[8] = {1024, 64, 1024, 64, 1024, 32, 1024, 160};
    const int Nd[8] = {64, 1024, 64, 1024, 32, 1024, 160, 1024};
    const void* srcs[8] = {w1, w2, a1, a2, v1, v2, g1, g2};
    bf16* dsts[8] = {w1t, w2t, a1t, a2t, v1t, v2t, g1t, g2t};
    int seg = 0, start = 0;
#pragma unroll
    for (int s2 = 0; s2 < 7; s2++)
      if (idx >= ends[s2]) { seg = s2 + 1; start = ends[s2]; }
    int local = idx - start;
    int K = Ks[seg], N = Nd[seg];
    int k = local / N, n = local - k * N;
    dsts[seg][(size_t)n * K + k] = f2b(ldin(srcs[seg], local, fl));
  }
}

// ---------------- shared MFMA GEMM core: C[M,N] = A[M,K] * B[N,K]^T ----------------
template<typename Epi>
DEVINL void gemm_core(const bf16* __restrict__ A, const bf16* __restrict__ Bt,
                      int K, int Brows, int m0, int n0, Epi&& epi)
{
  __shared__ short As[128 * 32];
  __shared__ short Bs[128 * 32];
  const int tid = threadIdx.x;
  const int wid = tid >> 6, lane = tid & 63;
  const int wr = (wid >> 1) * 64, wc = (wid & 1) * 64;

  f32x4 acc[4][4] = {};

  const int lrow = lane >> 2;
  const int lcol = (lane & 3) * 8;
  int arow0 = m0 + (wid * 2 + 0) * 16 + lrow;
  int arow1 = m0 + (wid * 2 + 1) * 16 + lrow;
  int brow0 = n0 + (wid * 2 + 0) * 16 + lrow; if (brow0 >= Brows) brow0 = Brows - 1;
  int brow1 = n0 + (wid * 2 + 1) * 16 + lrow; if (brow1 >= Brows) brow1 = Brows - 1;

  const short* Ag = (const short*)A;
  const short* Bg = (const short*)Bt;

  for (int kk = 0; kk < K; kk += 32) {
    __syncthreads();
    g2lds16(Ag + (size_t)arow0 * K + kk + lcol, As + (wid * 2 + 0) * 512);
    g2lds16(Ag + (size_t)arow1 * K + kk + lcol, As + (wid * 2 + 1) * 512);
    g2lds16(Bg + (size_t)brow0 * K + kk + lcol, Bs + (wid * 2 + 0) * 512);
    g2lds16(Bg + (size_t)brow1 * K + kk + lcol, Bs + (wid * 2 + 1) * 512);
    __syncthreads();
    bf16x8 af[4], bfr[4];
#pragma unroll
    for (int mi = 0; mi < 4; mi++)
      af[mi] = *(const bf16x8*)(As + (wr + mi * 16 + (lane & 15)) * 32 + (lane >> 4) * 8);
#pragma unroll
    for (int ni = 0; ni < 4; ni++)
      bfr[ni] = *(const bf16x8*)(Bs + (wc + ni * 16 + (lane & 15)) * 32 + (lane >> 4) * 8);
#pragma unroll
    for (int mi = 0; mi < 4; mi++)
#pragma unroll
      for (int ni = 0; ni < 4; ni++)
        acc[mi][ni] = __builtin_amdgcn_mfma_f32_16x16x32_bf16(af[mi], bfr[ni], acc[mi][ni], 0, 0, 0);
  }

  const int cl0 = lane & 15, r0 = (lane >> 4) * 4;
#pragma unroll
  for (int mi = 0; mi < 4; mi++)
#pragma unroll
    for (int ni = 0; ni < 4; ni++) {
      int col = n0 + wc + ni * 16 + cl0;
#pragma unroll
      for (int rr = 0; rr < 4; rr++)
        epi(m0 + wr + mi * 16 + r0 + rr, col, acc[mi][ni][rr]);
    }
}

// ---------------- stage1: xw@w1 tanh | xa@a1 | xv@v1 | xg@g1 sigm ----------------
__global__ __launch_bounds__(256)
void stage1_kernel(const bf16* xw, const bf16* xa, const bf16* xv, const bf16* xg,
                   const bf16* w1t, const bf16* a1t, const bf16* v1t, const bf16* g1t,
                   bf16* hw, bf16* ha, bf16* hv, bf16* hg)
{
  int y = blockIdx.y;
  int seg = (y <= 2) ? y : 3;
  int n0 = (y == 4) ? 128 : 0;
  const bf16* A  = seg == 0 ? xw  : seg == 1 ? xa  : seg == 2 ? xv  : xg;
  const bf16* Bt = seg == 0 ? w1t : seg == 1 ? a1t : seg == 2 ? v1t : g1t;
  int NS         = seg == 0 ? 64  : seg == 1 ? 64  : seg == 2 ? 32  : 160;
  bf16* out      = seg == 0 ? hw  : seg == 1 ? ha  : seg == 2 ? hv  : hg;
  gemm_core(A, Bt, 1024, NS, blockIdx.x * 128, n0, [&](int row, int col, float f) {
    if (col >= NS) return;
    if (seg == 0) f = tanhf(f);
    else if (seg == 3) f = sigm(f);
    out[(size_t)row * NS + col] = f2b(f);
  });
}

// ---------------- big r/k/v projections -> packed stream ----------------
__global__ __launch_bounds__(256)
void bigrkv_kernel(const bf16* xr, const bf16* xk, const bf16* xv,
                   const bf16* cWr, const bf16* cWk, const bf16* cWv,
                   bf16* __restrict__ STR)
{
  int z = blockIdx.z;
  const bf16* A  = z == 0 ? xr  : z == 1 ? xk  : xv;
  const bf16* Bt = z == 0 ? cWr : z == 1 ? cWk : cWv;
  gemm_core(A, Bt, 1024, 1024, blockIdx.x * 128, blockIdx.y * 128,
            [&](int row, int col, float f) {
    size_t sb = stream_sb(row, col >> 6);
    int n = col & 63;
    size_t off = (z == 2) ? (sb + 256 + n) : (sb + n * 4 + z);  // r->slot0 kraw->slot1 v->v
    STR[off] = f2b(f);
  });
}

// ---------------- stage2: wdec | asig->slot2 | vblend->v | G ----------------
__global__ __launch_bounds__(256)
void stage2_kernel(const bf16* hw, const bf16* ha, const bf16* hv, const bf16* hg,
                   const bf16* w2t, const bf16* a2t, const bf16* v2t, const bf16* g2t,
                   bf16* __restrict__ STR, float* __restrict__ STRf, float* __restrict__ G,
                   const void* w0, const void* a0, const void* v0p, const void* vfirst,
                   const int* __restrict__ flag)
{
  int fl = *flag;
  int z = blockIdx.z;
  const bf16* A  = z == 0 ? hw  : z == 1 ? ha  : z == 2 ? hv  : hg;
  const bf16* Bt = z == 0 ? w2t : z == 1 ? a2t : z == 2 ? v2t : g2t;
  int K          = z == 0 ? 64  : z == 1 ? 64  : z == 2 ? 32  : 160;
  gemm_core(A, Bt, K, 1024, blockIdx.x * 128, blockIdx.y * 128,
            [&](int row, int col, float f) {
    int n = col & 63;
    if (z == 0) {
      float zz = -(ldin(w0, col, fl) + f);
      float sp = fmaxf(zz, 0.f) + __logf(1.f + __expf(-fabsf(zz)));
      STRf[stream_sb(row, col >> 6) / 2 + 160 + n] = __expf(-__expf(-sp - 0.5f));
    } else if (z == 1) {
      STR[stream_sb(row, col >> 6) + n * 4 + 2] = f2b(sigm(ldin(a0, col, fl) + f));
    } else if (z == 2) {
      float sg = sigm(ldin(v0p, col, fl) + f);
      size_t pa = stream_sb(row, col >> 6) + 256 + n;
      float vr = b2f(STR[pa]);
      float vf = ldin(vfirst, (size_t)row * 1024 + col, fl);
      STR[pa] = f2b(vr + (vf - vr) * sg);
    } else {
      G[(size_t)row * 1024 + col] = f;
    }
  });
}

// ---------------- per-(t,h) finalize: kkn->slot2, b->slot3, kfinal->slot1 ----------------
__global__ __launch_bounds__(256)
void post_kernel(bf16* __restrict__ STR, const void* __restrict__ kkw,
                 const void* __restrict__ kaw, const int* __restrict__ flag) {
  int fl = *flag;
  int slot = blockIdx.x * 4 + (threadIdx.x >> 6);
  int tg = slot >> 4, h = slot & 15;
  int n = threadIdx.x & 63, c = h * 64 + n;
  size_t sb = stream_sb(tg, h);
  float kraw = b2f(STR[sb + n * 4 + 1]);
  float asig = b2f(STR[sb + n * 4 + 2]);
  float kk = kraw * ldin(kkw, c, fl);
  float ss = kk * kk;
  ss += __shfl_xor(ss, 1);  ss += __shfl_xor(ss, 2);  ss += __shfl_xor(ss, 4);
  ss += __shfl_xor(ss, 8);  ss += __shfl_xor(ss, 16); ss += __shfl_xor(ss, 32);
  float kkn = kk / fmaxf(sqrtf(ss), 1e-12f);
  STR[sb + n * 4 + 2] = f2b(kkn);
  STR[sb + n * 4 + 3] = f2b(-kkn * asig);
  STR[sb + n * 4 + 1] = f2b(kraw * (1.f + (asig - 1.f) * ldin(kaw, c, fl)));
}

// ---------------- sequential recurrence: LDS double-buffered ring ----------------
// 1024 single-wave blocks. blk = sib*64 + bh (16 sibs per bh, same XCD).
// Wave owns rows [sib*4,+4); lane: rl=lane>>4, jq=lane&15 (4 j's each).
// One global_load_lds (width16, 64 lanes) stages one 1024B step record; ring =
// 2 x 8 steps in LDS (16KB). Single wave -> no barrier; explicit vmcnt(8)
// after prefetch-issue guarantees the current buffer's 8 loads retired
// (vmem queue order: [cur loads(8), prev stores(<=8), next loads(8)]).
// Overreads <=8 steps past stream end (lands in pad) - benign.
#define CH 8
__global__ __launch_bounds__(64)
void recur_kernel(const char* __restrict__ STR, float* __restrict__ Y) {
  __shared__ __align__(16) char lds[2 * CH * 1024];
  int blk = blockIdx.x;
  int bh = blk & 63, sib = blk >> 6;
  int b = bh >> 4, h = bh & 15;
  int lane = threadIdx.x;
  int jq = lane & 15, rl = lane >> 4;
  int i = sib * 4 + rl;

  const char* gb = STR + (size_t)bh * (1024 * 1024) + lane * 16;
  float* yout = Y + (size_t)b * 1024 * 1024 + h * 64 + i;

  const char* prk = lds + jq * 32;            // rkab base (per-lane)
  const char* pv  = lds + 512 + i * 2;        // v base
  const char* pw  = lds + 640 + jq * 16;      // w base

#pragma unroll
  for (int d = 0; d < CH; ++d)
    g2lds16(gb + (size_t)d * 1024, lds + d * 1024);

  float S0 = 0.f, S1 = 0.f, S2 = 0.f, S3 = 0.f;

  for (int t0 = 0; t0 < 1024; t0 += CH) {
    int cur = (t0 >> 3) & 1;
    int cbase = cur * (CH * 1024);
    char* bufn = lds + (cur ^ 1) * (CH * 1024);
    // issue next CH step records into the other buffer (fire-and-forget)
#pragma unroll
    for (int d = 0; d < CH; ++d)
      g2lds16(gb + (size_t)(t0 + CH + d) * 1024, bufn + d * 1024);
    // drain everything older than the 8 just-issued loads -> current buf ready
    wait_vmcnt8();
    // compute CH steps from current buffer
#pragma unroll
    for (int d = 0; d < CH; ++d) {
      int so = cbase + d * 1024;
      uint4 m0 = *(const uint4*)(prk + so);
      uint4 m1 = *(const uint4*)(prk + so + 16);
      float4 wv = *(const float4*)(pw + so);
      unsigned short vu = *(const unsigned short*)(pv + so);
      float vi = bfbits2f(vu);
      float rx = lo16(m0.x), kx = hi16(m0.x), ax = lo16(m0.y), bx = hi16(m0.y);
      float ry = lo16(m0.z), ky = hi16(m0.z), ay = lo16(m0.w), by = hi16(m0.w);
      float rz = lo16(m1.x), kz = hi16(m1.x), az = lo16(m1.y), bz = hi16(m1.y);
      float rw = lo16(m1.z), kw = hi16(m1.z), aw = lo16(m1.w), bw = hi16(m1.w);

      float sa = (S0 * ax + S1 * ay) + (S2 * az + S3 * aw);
      sa = rowsum16(sa);
      S0 = S0 * wv.x + (sa * bx + vi * kx);
      S1 = S1 * wv.y + (sa * by + vi * ky);
      S2 = S2 * wv.z + (sa * bz + vi * kz);
      S3 = S3 * wv.w + (sa * bw + vi * kw);
      float y = (S0 * rx + S1 * ry) + (S2 * rz + S3 * rw);
      y = rowsum16(y);
      if (jq == 0) yout[(size_t)(t0 + d) * 1024] = y;
    }
  }
}

// ---------------- GroupNorm + residual + g gate ----------------
__global__ __launch_bounds__(256)
void gn_kernel(const float* __restrict__ Y, const bf16* __restrict__ STR,
               const float* __restrict__ G,
               const void* __restrict__ gw, const void* __restrict__ gb,
               const void* __restrict__ rk, const int* __restrict__ flag,
               bf16* __restrict__ Z)
{
  int fl = *flag;
  int slot = blockIdx.x * 4 + (threadIdx.x >> 6);
  int tg = slot >> 4, h = slot & 15;
  int n = threadIdx.x & 63, c = h * 64 + n;
  size_t sb = stream_sb(tg, h);
  float y = Y[(size_t)tg * 1024 + c];
  float rr = b2f(STR[sb + n * 4]), kf = b2f(STR[sb + n * 4 + 1]), vv = b2f(STR[sb + 256 + n]);
  float s1 = y, s2 = y * y, s3 = rr * kf * ldin(rk, c, fl);
#pragma unroll
  for (int m = 1; m < 64; m <<= 1) {
    s1 += __shfl_xor(s1, m);
    s2 += __shfl_xor(s2, m);
    s3 += __shfl_xor(s3, m);
  }
  float mu = s1 * 0.015625f;
  float var = s2 * 0.015625f - mu * mu;
  float xn = (y - mu) * rsqrtf(var + 0.00064f);
  float yn = xn * ldin(gw, c, fl) + ldin(gb, c, fl);
  yn += s3 * vv;
  Z[(size_t)tg * 1024 + c] = f2b(yn * G[(size_t)tg * 1024 + c]);
}

// ---------------- final output GEMM ----------------
__global__ __launch_bounds__(256)
void outgemm_kernel(const bf16* Z, const bf16* cWo,
                    float* oF, bf16* oB, const int* __restrict__ flag)
{
  int fl = *flag;
  gemm_core(Z, cWo, 1024, 1024, blockIdx.x * 128, blockIdx.y * 128,
            [&](int row, int col, float f) {
    if (fl) oF[(size_t)row * 1024 + col] = f;
    else    oB[(size_t)row * 1024 + col] = f2b(f);
  });
}

extern "C" void kernel_launch(void* const* d_in, const int* in_sizes, int n_in,
                              void* d_out, int out_size, void* d_ws, size_t ws_size,
                              hipStream_t stream)
{
  const void* x      = d_in[0];
  const void* vfirst = d_in[1];
  const void* m_r = d_in[2];  const void* m_w = d_in[3];
  const void* m_k = d_in[4];  const void* m_v = d_in[5];
  const void* m_a = d_in[6];  const void* m_g = d_in[7];
  const void* w0  = d_in[8];  const void* w1  = d_in[9];  const void* w2  = d_in[10];
  const void* a0  = d_in[11]; const void* a1  = d_in[12]; const void* a2  = d_in[13];
  const void* v0p = d_in[14]; const void* v1  = d_in[15]; const void* v2  = d_in[16];
  const void* g1  = d_in[17]; const void* g2  = d_in[18];
  const void* k_k = d_in[19]; const void* k_a = d_in[20]; const void* r_k = d_in[21];
  const void* W_r = d_in[22]; const void* W_k = d_in[23];
  const void* W_v = d_in[24]; const void* W_o = d_in[25];
  const void* gnw = d_in[26]; const void* gnb = d_in[27];
  (void)in_sizes; (void)n_in; (void)out_size; (void)ws_size;

  char* ws = (char*)d_ws;
  size_t off = 0;
  auto alloc = [&](size_t bytes) -> void* {
    void* p = ws + off; off += (bytes + 255) & ~(size_t)255; return p;
  };
  const size_t BTC2 = (size_t)4096 * 1024 * 2;
  int*  flag = (int*)alloc(256);
  bf16* cWr = (bf16*)alloc((size_t)1048576 * 2);
  bf16* cWk = (bf16*)alloc((size_t)1048576 * 2);
  bf16* cWv = (bf16*)alloc((size_t)1048576 * 2);
  bf16* cWo = (bf16*)alloc((size_t)1048576 * 2);
  bf16* w1t = (bf16*)alloc((size_t)65536 * 2);
  bf16* w2t = (bf16*)alloc((size_t)65536 * 2);
  bf16* a1t = (bf16*)alloc((size_t)65536 * 2);
  bf16* a2t = (bf16*)alloc((size_t)65536 * 2);
  bf16* v1t = (bf16*)alloc((size_t)32768 * 2);
  bf16* v2t = (bf16*)alloc((size_t)32768 * 2);
  bf16* g1t = (bf16*)alloc((size_t)163840 * 2);
  bf16* g2t = (bf16*)alloc((size_t)163840 * 2);
  bf16* xr = (bf16*)alloc(BTC2);
  bf16* xw = (bf16*)alloc(BTC2);
  bf16* xk = (bf16*)alloc(BTC2);
  bf16* xv = (bf16*)alloc(BTC2);
  bf16* xa = (bf16*)alloc(BTC2);
  bf16* xg = (bf16*)alloc(BTC2);
  char* STR = (char*)alloc((size_t)64 * 1024 * 1024 + 16384);  // packed [B*H][T][1024B] + overread pad
  bf16* hw  = (bf16*)alloc((size_t)4096 * 64 * 2);
  bf16* ha  = (bf16*)alloc((size_t)4096 * 64 * 2);
  bf16* hv  = (bf16*)alloc((size_t)4096 * 32 * 2);
  bf16* hg  = (bf16*)alloc((size_t)4096 * 160 * 2);
  // dead-buffer reuse (lifetimes verified by launch order):
  float* G = (float*)xr;   // over xr+xw; written by stage2 (after stage1/bigrkv consume)
  float* Y = (float*)xk;   // over xk+xv; written by recur
  bf16*  Z = xa;           // written by gn (after stage1 consumes xa)

  detect_kernel<<<1, 256, 0, stream>>>((const unsigned*)x, flag);
  prep_kernel<<<35328, 256, 0, stream>>>(
      x, m_r, m_w, m_k, m_v, m_a, m_g,
      W_r, W_k, W_v, W_o, cWr, cWk, cWv, cWo,
      w1, w2, a1, a2, v1, v2, g1, g2,
      w1t, w2t, a1t, a2t, v1t, v2t, g1t, g2t,
      flag, xr, xw, xk, xv, xa, xg);

  stage1_kernel<<<dim3(32, 5), 256, 0, stream>>>(xw, xa, xv, xg,
                                                 w1t, a1t, v1t, g1t, hw, ha, hv, hg);
  bigrkv_kernel<<<dim3(32, 8, 3), 256, 0, stream>>>(xr, xk, xv, cWr, cWk, cWv, (bf16*)STR);
  stage2_kernel<<<dim3(32, 8, 4), 256, 0, stream>>>(hw, ha, hv, hg,
                                                    w2t, a2t, v2t, g2t,
                                                    (bf16*)STR, (float*)STR, G,
                                                    w0, a0, v0p, vfirst, flag);
  post_kernel<<<16384, 256, 0, stream>>>((bf16*)STR, k_k, k_a, flag);
  recur_kernel<<<1024, 64, 0, stream>>>(STR, Y);
  gn_kernel<<<16384, 256, 0, stream>>>(Y, (bf16*)STR, G, gnw, gnb, r_k, flag, Z);
  outgemm_kernel<<<dim3(32, 8), 256, 0, stream>>>(Z, cWo, (float*)d_out, (bf16*)d_out, flag);
}